// Round 2
// baseline (33801.010 us; speedup 1.0000x reference)
//
#include <hip/hip_runtime.h>

// PRPN eval forward for MI355X. All float inputs are FP32 (verified: harness
// threshold 2e-2 == non-bf16 path), ids int32. Output = [y (T*B*D) | mask (T*B)] fp32.
//
// Structure:
//   k_zero      : zero recurrent state + barrier in ws
//   k_emb       : embedding gather + mask output
//   k_conv      : parsing conv (im2col GEMM, K=2304) + bias + BN(eval) + relu
//   k_gate      : grouped 1x1 conv -> gate, gate_next (sigmoid)
//   k_mg        : hard memory gates (hardtanh + cumprod over S)
//   k_gemm      : generic tiled GEMM C = A @ W^T + bias  (mode1: tanh-BN epilogue)
//   k_ln_rows   : row LayerNorm (precompute LN(e@Wih0+b))
//   k_scan      : persistent cooperative scan over T=192 (custom grid barrier,
//                 3 phases/step; wg<32 per-batch work, wg>=32 shared-weight GEMVs)
// ws requirement: ~96 MB (floats).

#define TT 192
#define TB 6144

constexpr size_t O_EMB    = 0;          // T*B*384 fp32
constexpr size_t O_IH0LN  = 2359296;    // T*B*1536 (raw then LN'd in place)
constexpr size_t O_KEY0E  = 11796480;   // T*B*384
constexpr size_t O_MG     = 14155776;   // T*B*15
constexpr size_t O_MGN    = 14247936;   // T*B*15
constexpr size_t O_H1     = 14340096;   // B*T x 384 (conv activations, b-major rows)
constexpr size_t O_GATEA  = 16699392;   // B*T
constexpr size_t O_GATEB  = 16705536;   // B*T
constexpr size_t O_OUTHS  = 16711680;   // T*B x 768 (h | sel)
constexpr size_t O_MEMH0  = 21430272;   // state (zeroed): B x 15 x 384 each
constexpr size_t O_MEMC0  = 21614592;
constexpr size_t O_MEMH1  = 21798912;
constexpr size_t O_MEMC1  = 21983232;
constexpr size_t O_PMEM   = 22167552;
constexpr size_t O_P0     = 22351872;   // B x 15 x 1536
constexpr size_t O_P1     = 23089152;
constexpr size_t O_HNEW0  = 23826432;   // B x 384
constexpr size_t O_HNEW1  = 23838720;
constexpr size_t O_IH1RAW = 23851008;   // B x 1536
constexpr size_t O_KEY1H  = 23900160;
constexpr size_t O_KEY0MH = 23912448;
constexpr size_t O_KEY1MH = 23924736;
constexpr size_t O_PKEYH  = 23937024;
constexpr size_t O_PKEYMH = 23949312;   // 2 x B x 384 (ping-pong)
constexpr size_t O_BAR    = 23973888;   // barrier counters
constexpr size_t O_WSEND  = 23973904;

__device__ __forceinline__ float sigmoidf(float x) { return 1.f / (1.f + expf(-x)); }

constexpr float BN_SC = 0.9999950000374997f;       // 1/sqrt(1+1e-5)
constexpr float INV_SQRT_H = 0.05103103630798288f; // 1/sqrt(384)

__device__ __forceinline__ float blockSum(float v, float* red) {
#pragma unroll
  for (int off = 32; off > 0; off >>= 1) v += __shfl_down(v, off, 64);
  __syncthreads();
  if ((threadIdx.x & 63) == 0) red[threadIdx.x >> 6] = v;
  __syncthreads();
  return red[0] + red[1] + red[2] + red[3];
}

// ---------------------------------------------------------------- k_zero
__global__ __launch_bounds__(256) void k_zero(float* p, int n) {
  int i = blockIdx.x * 256 + threadIdx.x;
  int stride = gridDim.x * 256;
  for (; i < n; i += stride) p[i] = 0.f;
}

// ---------------------------------------------------------------- k_emb (+mask)
__global__ __launch_bounds__(256) void k_emb(const int* ids, const float* emb_w,
                                             float* emb, float* out) {
  size_t idx = (size_t)blockIdx.x * 256 + threadIdx.x;
  size_t stride = (size_t)gridDim.x * 256;
  for (size_t i = idx; i < (size_t)TB * 384; i += stride) {
    size_t tb = i / 384, d = i - tb * 384;
    int id = ids[tb];
    emb[i] = emb_w[(size_t)id * 384 + d];
    if (i < TB) out[(size_t)TB * 384 + i] = (ids[i] != 0) ? 1.f : 0.f;
  }
}

// ---------------------------------------------------------------- k_conv (im2col GEMM)
// rows m = b*192+t, cols n = channel h, K = 2304 (kc*384+d). Epilogue: +bias, BN(eval), relu.
__global__ __launch_bounds__(256) void k_conv(const float* emb, const float* W1, const float* cbias,
                                              const float* bng, const float* bnb, float* h1) {
  __shared__ float As[32][68];
  __shared__ float Bs[32][68];
  int n0 = blockIdx.x * 64, m0 = blockIdx.y * 64;
  int tid = threadIdx.x;
  float acc[4][4] = {};
  int mi = tid >> 3, kq = tid & 7;
  int ni = tid >> 2, kb = tid & 3;
  for (int kk = 0; kk < 2304; kk += 32) {
    int kc = kk / 384, dbase = kk - kc * 384;
    __syncthreads();
#pragma unroll
    for (int p = 0; p < 2; ++p) {
      int m = m0 + mi + 32 * p;
      int b = m / 192, t = m - b * 192;
      int tt = t + kc - 5;
      float4 v = {0.f, 0.f, 0.f, 0.f};
      if (tt >= 0) v = *(const float4*)(emb + ((size_t)tt * 32 + b) * 384 + dbase + kq * 4);
      As[kq * 4 + 0][mi + 32 * p] = v.x; As[kq * 4 + 1][mi + 32 * p] = v.y;
      As[kq * 4 + 2][mi + 32 * p] = v.z; As[kq * 4 + 3][mi + 32 * p] = v.w;
    }
#pragma unroll
    for (int i = 0; i < 8; ++i) {
      int d = dbase + kb * 8 + i;
      Bs[kb * 8 + i][ni] = W1[(size_t)(n0 + ni) * 2304 + d * 6 + kc];
    }
    __syncthreads();
    int ty = tid >> 4, tx = tid & 15;
#pragma unroll
    for (int k = 0; k < 32; ++k) {
      float4 a = *(const float4*)(&As[k][ty * 4]);
      float4 bv = *(const float4*)(&Bs[k][tx * 4]);
      acc[0][0] += a.x * bv.x; acc[0][1] += a.x * bv.y; acc[0][2] += a.x * bv.z; acc[0][3] += a.x * bv.w;
      acc[1][0] += a.y * bv.x; acc[1][1] += a.y * bv.y; acc[1][2] += a.y * bv.z; acc[1][3] += a.y * bv.w;
      acc[2][0] += a.z * bv.x; acc[2][1] += a.z * bv.y; acc[2][2] += a.z * bv.z; acc[2][3] += a.z * bv.w;
      acc[3][0] += a.w * bv.x; acc[3][1] += a.w * bv.y; acc[3][2] += a.w * bv.z; acc[3][3] += a.w * bv.w;
    }
  }
  int ty = tid >> 4, tx = tid & 15;
#pragma unroll
  for (int i = 0; i < 4; ++i) {
    int m = m0 + ty * 4 + i;
#pragma unroll
    for (int j = 0; j < 4; ++j) {
      int n = n0 + tx * 4 + j;
      float v = acc[i][j] + cbias[n];
      v = bng[n] * v * BN_SC + bnb[n];
      h1[(size_t)m * 384 + n] = fmaxf(v, 0.f);
    }
  }
}

// ---------------------------------------------------------------- k_gate
__global__ __launch_bounds__(256) void k_gate(const float* h1, const float* w2, const float* b2,
                                              float* gA, float* gB) {
  __shared__ float red[8];
  int bt = blockIdx.x, tid = threadIdx.x;
  float v0 = 0.f, v1 = 0.f;
  if (tid < 192) {
    v0 = h1[(size_t)bt * 384 + tid] * w2[tid];
    v1 = h1[(size_t)bt * 384 + 192 + tid] * w2[192 + tid];
  }
  float s0 = blockSum(v0, red);
  float s1 = blockSum(v1, red);
  if (tid == 0) {
    gA[bt] = 1.f / (1.f + expf(-(s0 + b2[0])));
    gB[bt] = 1.f / (1.f + expf(-(s1 + b2[1])));
  }
}

// ---------------------------------------------------------------- k_mg (hard gates + cumprod)
__global__ __launch_bounds__(256) void k_mg(const float* gA, const float* gB, float* mg, float* mgn) {
  int idx = blockIdx.x * 256 + threadIdx.x;
  if (idx >= TB) return;
  int t = idx >> 5, b = idx & 31;
  float g = gA[b * 192 + t], gn = gB[b * 192 + t];
  float p = 1.f, pn = 1.f;
  for (int k = 0; k < 15; ++k) {
    float ghat = (k <= t) ? gA[b * 192 + t - k] : 1e9f;
    float u = fminf(fmaxf((g - ghat) / 0.1f * 2.f + 1.f, -1.f), 1.f);
    float un = fminf(fmaxf((gn - ghat) / 0.1f * 2.f + 1.f, -1.f), 1.f);
    p *= (u + 1.f) * 0.5f;
    pn *= (un + 1.f) * 0.5f;
    mg[(size_t)idx * 15 + k] = p;
    mgn[(size_t)idx * 15 + k] = pn;
  }
}

// ---------------------------------------------------------------- k_gemm (generic)
// C[M,N] = A[M,K] @ W[N,ldw]^T + bias. mode0: fp32 store; mode1: tanh(BN(y)) epilogue.
__global__ __launch_bounds__(256) void k_gemm(const float* A, int lda, const float* W, int ldw,
                                              const float* bias, float* Cf, int ldc, int K, int mode,
                                              const float* bng, const float* bnb, float* Cb) {
  __shared__ float As[32][68];
  __shared__ float Bs[32][68];
  int n0 = blockIdx.x * 64, m0 = blockIdx.y * 64;
  int tid = threadIdx.x;
  float acc[4][4] = {};
  int mi = tid >> 3, kq = tid & 7;
  int ni = tid >> 2, kb = tid & 3;
  for (int kk = 0; kk < K; kk += 32) {
    __syncthreads();
#pragma unroll
    for (int p = 0; p < 2; ++p) {
      int m = m0 + mi + 32 * p;
      float4 v = *(const float4*)(A + (size_t)m * lda + kk + kq * 4);
      As[kq * 4 + 0][mi + 32 * p] = v.x; As[kq * 4 + 1][mi + 32 * p] = v.y;
      As[kq * 4 + 2][mi + 32 * p] = v.z; As[kq * 4 + 3][mi + 32 * p] = v.w;
    }
    {
      const float* wp = W + (size_t)(n0 + ni) * ldw + kk + kb * 8;
      float4 q0 = *(const float4*)(wp);
      float4 q1 = *(const float4*)(wp + 4);
      Bs[kb * 8 + 0][ni] = q0.x; Bs[kb * 8 + 1][ni] = q0.y;
      Bs[kb * 8 + 2][ni] = q0.z; Bs[kb * 8 + 3][ni] = q0.w;
      Bs[kb * 8 + 4][ni] = q1.x; Bs[kb * 8 + 5][ni] = q1.y;
      Bs[kb * 8 + 6][ni] = q1.z; Bs[kb * 8 + 7][ni] = q1.w;
    }
    __syncthreads();
    int ty = tid >> 4, tx = tid & 15;
#pragma unroll
    for (int k = 0; k < 32; ++k) {
      float4 a = *(const float4*)(&As[k][ty * 4]);
      float4 bv = *(const float4*)(&Bs[k][tx * 4]);
      acc[0][0] += a.x * bv.x; acc[0][1] += a.x * bv.y; acc[0][2] += a.x * bv.z; acc[0][3] += a.x * bv.w;
      acc[1][0] += a.y * bv.x; acc[1][1] += a.y * bv.y; acc[1][2] += a.y * bv.z; acc[1][3] += a.y * bv.w;
      acc[2][0] += a.z * bv.x; acc[2][1] += a.z * bv.y; acc[2][2] += a.z * bv.z; acc[2][3] += a.z * bv.w;
      acc[3][0] += a.w * bv.x; acc[3][1] += a.w * bv.y; acc[3][2] += a.w * bv.z; acc[3][3] += a.w * bv.w;
    }
  }
  int ty = tid >> 4, tx = tid & 15;
#pragma unroll
  for (int i = 0; i < 4; ++i) {
    int m = m0 + ty * 4 + i;
#pragma unroll
    for (int j = 0; j < 4; ++j) {
      int n = n0 + tx * 4 + j;
      float v = acc[i][j];
      if (bias) v += bias[n];
      if (mode == 0) Cf[(size_t)m * ldc + n] = v;
      else Cb[(size_t)m * ldc + n] = tanhf(bng[n] * v * BN_SC + bnb[n]);
    }
  }
}

// ---------------------------------------------------------------- k_ln_rows (n=1536, unbiased, eps on std)
__global__ __launch_bounds__(256) void k_ln_rows(float* X, const float* g, const float* bt) {
  __shared__ float red[8];
  float* x = X + (size_t)blockIdx.x * 1536;
  int tid = threadIdx.x;
  float ps = 0.f;
  for (int i = tid; i < 1536; i += 256) ps += x[i];
  float mu = blockSum(ps, red) * (1.f / 1536.f);
  ps = 0.f;
  for (int i = tid; i < 1536; i += 256) { float d = x[i] - mu; ps += d * d; }
  float inv = 1.f / (sqrtf(blockSum(ps, red) * (1.f / 1535.f)) + 1e-6f);
  for (int i = tid; i < 1536; i += 256) x[i] = g[i] * (x[i] - mu) * inv + bt[i];
}

// ---------------------------------------------------------------- scan kernel
struct ScanArgs {
  float* ws;
  const float *r_whh, *r_bhh, *r_lnhh_g, *r_lnhh_b, *r_lnih_g, *r_lnih_b;
  const float *r_lnc_g, *r_lnc_b, *r_wih, *r_bih, *r_proj_w, *r_proj_b;
  const float *p_proj_w, *p_proj_b;
};

struct GJob { const float* W; int ldw; int koff; const float* bias; float* dst; int rstride; int ncols; };

__device__ __forceinline__ void resolveJob(const GJob* J, int col, const float*& W, int& ldw, int& koff,
                                           const float*& bias, float*& dst, int& rstride, int& cc) {
  int c = col;
#pragma unroll
  for (int j = 0; j < 4; ++j) {
    if (c < J[j].ncols) {
      W = J[j].W; ldw = J[j].ldw; koff = J[j].koff; bias = J[j].bias;
      dst = J[j].dst; rstride = J[j].rstride; cc = c; return;
    }
    c -= J[j].ncols;
  }
  W = J[0].W; ldw = J[0].ldw; koff = J[0].koff; bias = J[0].bias;
  dst = J[0].dst; rstride = J[0].rstride; cc = 0;
}

__device__ void grid_barrier(unsigned* bar) {
  __syncthreads();
  if (threadIdx.x == 0) {
    __threadfence();
    unsigned gen = __hip_atomic_load(&bar[1], __ATOMIC_RELAXED, __HIP_MEMORY_SCOPE_AGENT);
    unsigned arr = __hip_atomic_fetch_add(&bar[0], 1u, __ATOMIC_ACQ_REL, __HIP_MEMORY_SCOPE_AGENT);
    if (arr == 127u) {
      __hip_atomic_store(&bar[0], 0u, __ATOMIC_RELAXED, __HIP_MEMORY_SCOPE_AGENT);
      __hip_atomic_store(&bar[1], gen + 1u, __ATOMIC_RELEASE, __HIP_MEMORY_SCOPE_AGENT);
    } else {
      while (__hip_atomic_load(&bar[1], __ATOMIC_ACQUIRE, __HIP_MEMORY_SCOPE_AGENT) == gen)
        __builtin_amdgcn_s_sleep(1);
    }
    __threadfence();
  }
  __syncthreads();
}

// weight-shared GEMV phase: cols split over 96 wgs, K=384 split over 8 thread-groups,
// partials reduced via LDS (red: 8*28*32 <= 7168 floats).
__device__ void gemm_phase(const float* src, const GJob* J, int NC, int gwg, float* red) {
  const int tid = threadIdx.x;
  const int b = tid & 31, cg = tid >> 5;
  const int colsPer = NC / 96;
  const int base = gwg * colsPer;
  const int k0 = cg * 48;
  float xr[48];
  const float* xp = src + b * 384 + k0;
#pragma unroll
  for (int q = 0; q < 12; ++q) {
    float4 v = *(const float4*)(xp + q * 4);
    xr[q * 4 + 0] = v.x; xr[q * 4 + 1] = v.y; xr[q * 4 + 2] = v.z; xr[q * 4 + 3] = v.w;
  }
#pragma unroll
  for (int ci = 0; ci < 28; ++ci) {
    if (ci >= colsPer) break;
    const float* W; int ldw, koff; const float* bias; float* dst; int rstride; int cc;
    resolveJob(J, base + ci, W, ldw, koff, bias, dst, rstride, cc);
    const float* wr = W + (size_t)cc * ldw + koff + k0;
    float a = 0.f;
#pragma unroll
    for (int q = 0; q < 12; ++q) {
      float4 w = *(const float4*)(wr + q * 4);
      a += w.x * xr[q * 4 + 0] + w.y * xr[q * 4 + 1]
         + w.z * xr[q * 4 + 2] + w.w * xr[q * 4 + 3];
    }
    red[(cg * colsPer + ci) * 32 + b] = a;
  }
  __syncthreads();
  const int pairs = colsPer * 32;
  for (int pi = tid; pi < pairs; pi += 256) {
    int ci = pi >> 5, bb = pi & 31;
    float s = 0.f;
#pragma unroll
    for (int g = 0; g < 8; ++g) s += red[(g * colsPer + ci) * 32 + bb];
    const float* W; int ldw, koff; const float* bias; float* dst; int rstride; int cc;
    resolveJob(J, base + ci, W, ldw, koff, bias, dst, rstride, cc);
    if (bias) s += bias[cc];
    dst[(size_t)bb * rstride + cc] = s;
  }
  __syncthreads();
}

// per-batch phase: attention over memory (msoftmax with hard gate), P-cache combine,
// two LayerNorms, LSTM cell, LN(c), memory append.
__device__ void per_b_layer(int layer, int t, int b, const ScanArgs& A, float* sm) {
  float* ws = A.ws;
  const int tid = threadIdx.x;
  const size_t tb = (size_t)t * 32 + b;
  float* memh = ws + (layer ? O_MEMH1 : O_MEMH0) + (size_t)b * 15 * 384;
  float* memc = ws + (layer ? O_MEMC1 : O_MEMC0) + (size_t)b * 15 * 384;
  float* P = ws + (layer ? O_P1 : O_P0) + (size_t)b * 15 * 1536;
  float* keyl = sm; float* logit = sm + 384; float* att = sm + 400; float* red = sm + 416;
  float* ghh = sm + 448; float* gih = sm + 1984; float* selc = sm + 3520;
  float* cnew = sm + 3904; float* ogat = sm + 4288;

  for (int h = tid; h < 384; h += 256) {
    float k1, k2;
    if (layer == 0) { k1 = ws[O_KEY0E + tb * 384 + h]; k2 = ws[O_KEY0MH + (size_t)b * 384 + h]; }
    else { k1 = ws[O_KEY1H + (size_t)b * 384 + h]; k2 = ws[O_KEY1MH + (size_t)b * 384 + h]; }
    keyl[h] = k1 + k2;
  }
  __syncthreads();
  {
    int s = tid >> 4, l = tid & 15;
    if (s < 15) {
      const float* mh = memh + ((t + s) % 15) * 384;
      float p = 0.f;
      for (int k = l; k < 384; k += 16) p += mh[k] * keyl[k];
      p += __shfl_down(p, 8, 64); p += __shfl_down(p, 4, 64);
      p += __shfl_down(p, 2, 64); p += __shfl_down(p, 1, 64);
      if (l == 0) logit[s] = p * INV_SQRT_H;
    }
  }
  __syncthreads();
  if (tid == 0) {
    const float* mgp = ws + O_MG + tb * 15;
    float m = logit[0];
    for (int i = 1; i < 15; ++i) m = fmaxf(m, logit[i]);
    float sum = 0.f;
    for (int i = 0; i < 15; ++i) { float e = expf(logit[i] - m) * mgp[i]; att[i] = e; sum += e; }
    float inv = 1.f / (sum + 1e-8f);
    for (int i = 0; i < 15; ++i) att[i] *= inv;
  }
  __syncthreads();
  float av[15]; int pidx[15];
#pragma unroll
  for (int i = 0; i < 15; ++i) { av[i] = att[i]; pidx[i] = (t + i) % 15; }
  const float* bhh = A.r_bhh + layer * 1536;
  for (int n = tid; n < 1536; n += 256) {
    float acc = bhh[n];
#pragma unroll
    for (int i = 0; i < 15; ++i) acc += av[i] * P[(size_t)pidx[i] * 1536 + n];
    ghh[n] = acc;
  }
  for (int h = tid; h < 384; h += 256) {
    float acc = 0.f;
#pragma unroll
    for (int i = 0; i < 15; ++i) acc += av[i] * memc[pidx[i] * 384 + h];
    selc[h] = acc;
  }
  if (layer) {
    for (int n = tid; n < 1536; n += 256) gih[n] = ws[O_IH1RAW + (size_t)b * 1536 + n];
  }
  __syncthreads();
  float ps = 0.f;
  for (int n = tid; n < 1536; n += 256) ps += ghh[n];
  float mu_hh = blockSum(ps, red) * (1.f / 1536.f);
  ps = 0.f;
  for (int n = tid; n < 1536; n += 256) { float d = ghh[n] - mu_hh; ps += d * d; }
  float inv_hh = 1.f / (sqrtf(blockSum(ps, red) * (1.f / 1535.f)) + 1e-6f);
  float mu_ih = 0.f, inv_ih = 0.f;
  if (layer) {
    ps = 0.f;
    for (int n = tid; n < 1536; n += 256) ps += gih[n];
    mu_ih = blockSum(ps, red) * (1.f / 1536.f);
    ps = 0.f;
    for (int n = tid; n < 1536; n += 256) { float d = gih[n] - mu_ih; ps += d * d; }
    inv_ih = 1.f / (sqrtf(blockSum(ps, red) * (1.f / 1535.f)) + 1e-6f);
  }
  const float *hg = A.r_lnhh_g + layer * 1536, *hb = A.r_lnhh_b + layer * 1536;
  const float *ig = A.r_lnih_g + 1536, *ib = A.r_lnih_b + 1536;
  for (int h = tid; h < 384; h += 256) {
    float gi, gf, gc, go;
    if (layer == 0) {
      const float* ihr = ws + O_IH0LN + tb * 1536;
      gi = ihr[h]; gf = ihr[384 + h]; gc = ihr[768 + h]; go = ihr[1152 + h];
    } else {
      gi = ig[h] * (gih[h] - mu_ih) * inv_ih + ib[h];
      gf = ig[384 + h] * (gih[384 + h] - mu_ih) * inv_ih + ib[384 + h];
      gc = ig[768 + h] * (gih[768 + h] - mu_ih) * inv_ih + ib[768 + h];
      go = ig[1152 + h] * (gih[1152 + h] - mu_ih) * inv_ih + ib[1152 + h];
    }
    gi += hg[h] * (ghh[h] - mu_hh) * inv_hh + hb[h];
    gf += hg[384 + h] * (ghh[384 + h] - mu_hh) * inv_hh + hb[384 + h];
    gc += hg[768 + h] * (ghh[768 + h] - mu_hh) * inv_hh + hb[768 + h];
    go += hg[1152 + h] * (ghh[1152 + h] - mu_hh) * inv_hh + hb[1152 + h];
    float c = sigmoidf(gf) * selc[h] + sigmoidf(gi) * tanhf(gc);
    cnew[h] = c; ogat[h] = go;
  }
  __syncthreads();
  ps = 0.f;
  for (int h = tid; h < 384; h += 256) ps += cnew[h];
  float mu_c = blockSum(ps, red) * (1.f / 384.f);
  ps = 0.f;
  for (int h = tid; h < 384; h += 256) { float d = cnew[h] - mu_c; ps += d * d; }
  float inv_c = 1.f / (sqrtf(blockSum(ps, red) * (1.f / 383.f)) + 1e-6f);
  const float *lcg = A.r_lnc_g + layer * 384, *lcb = A.r_lnc_b + layer * 384;
  const int slot = t % 15;
  for (int h = tid; h < 384; h += 256) {
    float hn = sigmoidf(ogat[h]) * tanhf(lcg[h] * (cnew[h] - mu_c) * inv_c + lcb[h]);
    memh[slot * 384 + h] = hn;
    memc[slot * 384 + h] = cnew[h];
    if (layer == 0) ws[O_HNEW0 + (size_t)b * 384 + h] = hn;
    else { ws[O_HNEW1 + (size_t)b * 384 + h] = hn; ws[O_OUTHS + tb * 768 + h] = hn; }
  }
}

__device__ void per_b_predict(int tau, int b, const ScanArgs& A, float* sm) {
  float* ws = A.ws;
  const int tid = threadIdx.x;
  const size_t tb = (size_t)tau * 32 + b;
  float* pmem = ws + O_PMEM + (size_t)b * 15 * 384;
  float* keyl = sm; float* logit = sm + 384; float* att = sm + 400;
  for (int h = tid; h < 384; h += 256)
    keyl[h] = ws[O_PKEYH + (size_t)b * 384 + h] + ws[O_PKEYMH + (size_t)(tau & 1) * 12288 + (size_t)b * 384 + h];
  __syncthreads();
  {
    int s = tid >> 4, l = tid & 15;
    if (s < 15) {
      const float* mh = pmem + ((tau + s) % 15) * 384;
      float p = 0.f;
      for (int k = l; k < 384; k += 16) p += mh[k] * keyl[k];
      p += __shfl_down(p, 8, 64); p += __shfl_down(p, 4, 64);
      p += __shfl_down(p, 2, 64); p += __shfl_down(p, 1, 64);
      if (l == 0) logit[s] = p * INV_SQRT_H;
    }
  }
  __syncthreads();
  if (tid == 0) {
    const float* mgp = ws + O_MGN + tb * 15;
    float m = logit[0];
    for (int i = 1; i < 15; ++i) m = fmaxf(m, logit[i]);
    float sum = 0.f;
    for (int i = 0; i < 15; ++i) { float e = expf(logit[i] - m) * mgp[i]; att[i] = e; sum += e; }
    float inv = 1.f / (sum + 1e-8f);
    for (int i = 0; i < 15; ++i) att[i] *= inv;
  }
  __syncthreads();
  float av[15]; int pidx[15];
#pragma unroll
  for (int i = 0; i < 15; ++i) { av[i] = att[i]; pidx[i] = (tau + i) % 15; }
  for (int h = tid; h < 384; h += 256) {
    float acc = 0.f;
#pragma unroll
    for (int i = 0; i < 15; ++i) acc += av[i] * pmem[pidx[i] * 384 + h];
    ws[O_OUTHS + tb * 768 + 384 + h] = acc;
  }
  __syncthreads();  // all pmem reads done before append overwrites oldest slot
  for (int h = tid; h < 384; h += 256)
    pmem[(tau % 15) * 384 + h] = ws[O_HNEW1 + (size_t)b * 384 + h];
}

__global__ __launch_bounds__(256) void k_scan(ScanArgs A) {
  __shared__ float sm[7424];
  float* ws = A.ws;
  unsigned* bar = (unsigned*)(ws + O_BAR);
  const int wg = blockIdx.x;
  for (int t = 0; t <= TT; ++t) {
    // ---- Phase 1: per-b layer0 | GEMVs from h_new1(t-1) ----
    if (wg < 32) {
      if (t < TT) per_b_layer(0, t, wg, A, sm);
    } else {
      GJob J[4] = {
        { A.r_whh + 589824, 384, 0, nullptr, ws + O_P1 + (size_t)((t + 14) % 15) * 1536, 23040, 1536 },
        { A.r_proj_w + 294912, 768, 384, nullptr, ws + O_KEY1MH, 384, 384 },
        { A.p_proj_w, 768, 0, A.p_proj_b, ws + O_PKEYH, 384, 384 },
        { A.p_proj_w, 768, 384, nullptr, ws + O_PKEYMH + (size_t)(t & 1) * 12288, 384, 384 },
      };
      gemm_phase(ws + O_HNEW1, J, 2688, wg - 32, sm);
    }
    grid_barrier(bar);
    // ---- Phase 2: per-b predict-att(t-1) | GEMVs from h_new0(t) ----
    if (wg < 32) {
      if (t >= 1) per_b_predict(t - 1, wg, A, sm);
    } else if (t < TT) {
      GJob J[4] = {
        { A.r_wih + 589824, 384, 0, A.r_bih + 1536, ws + O_IH1RAW, 1536, 1536 },
        { A.r_proj_w + 294912, 768, 0, A.r_proj_b + 384, ws + O_KEY1H, 384, 384 },
        { nullptr, 0, 0, nullptr, nullptr, 0, 0 },
        { nullptr, 0, 0, nullptr, nullptr, 0, 0 },
      };
      gemm_phase(ws + O_HNEW0, J, 1920, wg - 32, sm);
    }
    if (t == TT) break;
    grid_barrier(bar);
    // ---- Phase 3: per-b layer1 | GEMVs from h_new0(t) for next step ----
    if (wg < 32) {
      per_b_layer(1, t, wg, A, sm);
    } else {
      GJob J[4] = {
        { A.r_whh, 384, 0, nullptr, ws + O_P0 + (size_t)(t % 15) * 1536, 23040, 1536 },
        { A.r_proj_w, 768, 384, nullptr, ws + O_KEY0MH, 384, 384 },
        { nullptr, 0, 0, nullptr, nullptr, 0, 0 },
        { nullptr, 0, 0, nullptr, nullptr, 0, 0 },
      };
      gemm_phase(ws + O_HNEW0, J, 1920, wg - 32, sm);
    }
    grid_barrier(bar);
  }
}

// ---------------------------------------------------------------- launch
extern "C" void kernel_launch(void* const* d_in, const int* in_sizes, int n_in,
                              void* d_out, int out_size, void* d_ws, size_t ws_size,
                              hipStream_t stream) {
  const int* ids = (const int*)d_in[0];
  const float* emb_w = (const float*)d_in[1];
  const float* pconv1_w = (const float*)d_in[2];
  const float* pconv1_b = (const float*)d_in[3];
  const float* pbn_g = (const float*)d_in[4];
  const float* pbn_b = (const float*)d_in[5];
  const float* pconv2_w = (const float*)d_in[6];
  const float* pconv2_b = (const float*)d_in[7];
  const float* r_wih = (const float*)d_in[8];
  const float* r_bih = (const float*)d_in[9];
  const float* r_whh = (const float*)d_in[10];
  const float* r_bhh = (const float*)d_in[11];
  const float* r_lnih_g = (const float*)d_in[12];
  const float* r_lnih_b = (const float*)d_in[13];
  const float* r_lnhh_g = (const float*)d_in[14];
  const float* r_lnhh_b = (const float*)d_in[15];
  const float* r_lnc_g = (const float*)d_in[16];
  const float* r_lnc_b = (const float*)d_in[17];
  const float* r_proj_w = (const float*)d_in[18];
  const float* r_proj_b = (const float*)d_in[19];
  const float* p_proj_w = (const float*)d_in[20];
  const float* p_proj_b = (const float*)d_in[21];
  const float* p_ffd_w = (const float*)d_in[22];
  const float* p_ffd_b = (const float*)d_in[23];
  const float* p_bn_g = (const float*)d_in[24];
  const float* p_bn_b = (const float*)d_in[25];
  float* ws = (float*)d_ws;
  float* out = (float*)d_out;

  k_zero<<<1024, 256, 0, stream>>>(ws + O_MEMH0, (int)(O_WSEND - O_MEMH0));
  k_emb<<<4096, 256, 0, stream>>>(ids, emb_w, ws + O_EMB, out);
  k_conv<<<dim3(6, 96), 256, 0, stream>>>(ws + O_EMB, pconv1_w, pconv1_b, pbn_g, pbn_b, ws + O_H1);
  k_gate<<<6144, 256, 0, stream>>>(ws + O_H1, pconv2_w, pconv2_b, ws + O_GATEA, ws + O_GATEB);
  k_mg<<<24, 256, 0, stream>>>(ws + O_GATEA, ws + O_GATEB, ws + O_MG, ws + O_MGN);
  // precompute LN(e@Wih0+b) and key0_e = e@proj0_h + b for all t
  k_gemm<<<dim3(24, 96), 256, 0, stream>>>(ws + O_EMB, 384, r_wih, 384, r_bih,
                                           ws + O_IH0LN, 1536, 384, 0, nullptr, nullptr, nullptr);
  k_gemm<<<dim3(6, 96), 256, 0, stream>>>(ws + O_EMB, 384, r_proj_w, 768, r_proj_b,
                                          ws + O_KEY0E, 384, 384, 0, nullptr, nullptr, nullptr);
  k_ln_rows<<<6144, 256, 0, stream>>>(ws + O_IH0LN, r_lnih_g, r_lnih_b);
  ScanArgs SA{ws, r_whh, r_bhh, r_lnhh_g, r_lnhh_b, r_lnih_g, r_lnih_b,
              r_lnc_g, r_lnc_b, r_wih, r_bih, r_proj_w, r_proj_b, p_proj_w, p_proj_b};
  k_scan<<<128, 256, 0, stream>>>(SA);
  // head: y = tanh(BN(flat @ p_ffd^T + b)) -> out
  k_gemm<<<dim3(6, 96), 256, 0, stream>>>(ws + O_OUTHS, 768, p_ffd_w, 768, p_ffd_b,
                                          nullptr, 384, 768, 1, p_bn_g, p_bn_b, out);
}

// Round 3
// 25266.046 us; speedup vs baseline: 1.3378x; 1.3378x over previous
//
#include <hip/hip_runtime.h>

// PRPN eval forward for MI355X. All float inputs are FP32, ids int32.
// Output = [y (T*B*D) | mask (T*B)] fp32.
//
// R3 change vs R2: k_scan's grid barrier + cross-wg exchange no longer use
// agent-scope acquire/release (which emit buffer_inv / buffer_wbl2 = full
// per-XCD L2 invalidate/writeback per phase -> 56us/phase, 2.6GB HBM writes).
// Exchanged buffers now use RELAXED agent-scope atomics (sc0+sc1: bypass the
// non-coherent per-XCD L2, served at the LLC coherence point); private state
// and weights stay plain and L2-resident. Barrier = relaxed atomics + the
// vmcnt(0) drain __syncthreads() already performs.

#define TT 192
#define TB 6144

constexpr size_t O_EMB    = 0;          // T*B*384 fp32
constexpr size_t O_IH0LN  = 2359296;    // T*B*1536 (raw then LN'd in place)
constexpr size_t O_KEY0E  = 11796480;   // T*B*384
constexpr size_t O_MG     = 14155776;   // T*B*15
constexpr size_t O_MGN    = 14247936;   // T*B*15
constexpr size_t O_H1     = 14340096;   // B*T x 384 (conv activations, b-major rows)
constexpr size_t O_GATEA  = 16699392;   // B*T
constexpr size_t O_GATEB  = 16705536;   // B*T
constexpr size_t O_OUTHS  = 16711680;   // T*B x 768 (h | sel)
constexpr size_t O_MEMH0  = 21430272;   // state (zeroed): B x 15 x 384 each
constexpr size_t O_MEMC0  = 21614592;
constexpr size_t O_MEMH1  = 21798912;
constexpr size_t O_MEMC1  = 21983232;
constexpr size_t O_PMEM   = 22167552;
constexpr size_t O_P0     = 22351872;   // B x 15 x 1536
constexpr size_t O_P1     = 23089152;
constexpr size_t O_HNEW0  = 23826432;   // B x 384
constexpr size_t O_HNEW1  = 23838720;
constexpr size_t O_IH1RAW = 23851008;   // B x 1536
constexpr size_t O_KEY1H  = 23900160;
constexpr size_t O_KEY0MH = 23912448;
constexpr size_t O_KEY1MH = 23924736;
constexpr size_t O_PKEYH  = 23937024;
constexpr size_t O_PKEYMH = 23949312;   // 2 x B x 384 (ping-pong)
constexpr size_t O_BAR    = 23973888;   // barrier counters
constexpr size_t O_WSEND  = 23973904;

__device__ __forceinline__ float sigmoidf(float x) { return 1.f / (1.f + expf(-x)); }

// LLC-coherent (bypass per-XCD L2) relaxed accessors for cross-wg exchange.
__device__ __forceinline__ float ldx(const float* p) {
  return __hip_atomic_load(p, __ATOMIC_RELAXED, __HIP_MEMORY_SCOPE_AGENT);
}
__device__ __forceinline__ void stx(float* p, float v) {
  __hip_atomic_store(p, v, __ATOMIC_RELAXED, __HIP_MEMORY_SCOPE_AGENT);
}

constexpr float BN_SC = 0.9999950000374997f;       // 1/sqrt(1+1e-5)
constexpr float INV_SQRT_H = 0.05103103630798288f; // 1/sqrt(384)

__device__ __forceinline__ float blockSum(float v, float* red) {
#pragma unroll
  for (int off = 32; off > 0; off >>= 1) v += __shfl_down(v, off, 64);
  __syncthreads();
  if ((threadIdx.x & 63) == 0) red[threadIdx.x >> 6] = v;
  __syncthreads();
  return red[0] + red[1] + red[2] + red[3];
}

// ---------------------------------------------------------------- k_zero
__global__ __launch_bounds__(256) void k_zero(float* p, int n) {
  int i = blockIdx.x * 256 + threadIdx.x;
  int stride = gridDim.x * 256;
  for (; i < n; i += stride) p[i] = 0.f;
}

// ---------------------------------------------------------------- k_emb (+mask)
__global__ __launch_bounds__(256) void k_emb(const int* ids, const float* emb_w,
                                             float* emb, float* out) {
  size_t idx = (size_t)blockIdx.x * 256 + threadIdx.x;
  size_t stride = (size_t)gridDim.x * 256;
  for (size_t i = idx; i < (size_t)TB * 384; i += stride) {
    size_t tb = i / 384, d = i - tb * 384;
    int id = ids[tb];
    emb[i] = emb_w[(size_t)id * 384 + d];
    if (i < TB) out[(size_t)TB * 384 + i] = (ids[i] != 0) ? 1.f : 0.f;
  }
}

// ---------------------------------------------------------------- k_conv (im2col GEMM)
__global__ __launch_bounds__(256) void k_conv(const float* emb, const float* W1, const float* cbias,
                                              const float* bng, const float* bnb, float* h1) {
  __shared__ float As[32][68];
  __shared__ float Bs[32][68];
  int n0 = blockIdx.x * 64, m0 = blockIdx.y * 64;
  int tid = threadIdx.x;
  float acc[4][4] = {};
  int mi = tid >> 3, kq = tid & 7;
  int ni = tid >> 2, kb = tid & 3;
  for (int kk = 0; kk < 2304; kk += 32) {
    int kc = kk / 384, dbase = kk - kc * 384;
    __syncthreads();
#pragma unroll
    for (int p = 0; p < 2; ++p) {
      int m = m0 + mi + 32 * p;
      int b = m / 192, t = m - b * 192;
      int tt = t + kc - 5;
      float4 v = {0.f, 0.f, 0.f, 0.f};
      if (tt >= 0) v = *(const float4*)(emb + ((size_t)tt * 32 + b) * 384 + dbase + kq * 4);
      As[kq * 4 + 0][mi + 32 * p] = v.x; As[kq * 4 + 1][mi + 32 * p] = v.y;
      As[kq * 4 + 2][mi + 32 * p] = v.z; As[kq * 4 + 3][mi + 32 * p] = v.w;
    }
#pragma unroll
    for (int i = 0; i < 8; ++i) {
      int d = dbase + kb * 8 + i;
      Bs[kb * 8 + i][ni] = W1[(size_t)(n0 + ni) * 2304 + d * 6 + kc];
    }
    __syncthreads();
    int ty = tid >> 4, tx = tid & 15;
#pragma unroll
    for (int k = 0; k < 32; ++k) {
      float4 a = *(const float4*)(&As[k][ty * 4]);
      float4 bv = *(const float4*)(&Bs[k][tx * 4]);
      acc[0][0] += a.x * bv.x; acc[0][1] += a.x * bv.y; acc[0][2] += a.x * bv.z; acc[0][3] += a.x * bv.w;
      acc[1][0] += a.y * bv.x; acc[1][1] += a.y * bv.y; acc[1][2] += a.y * bv.z; acc[1][3] += a.y * bv.w;
      acc[2][0] += a.z * bv.x; acc[2][1] += a.z * bv.y; acc[2][2] += a.z * bv.z; acc[2][3] += a.z * bv.w;
      acc[3][0] += a.w * bv.x; acc[3][1] += a.w * bv.y; acc[3][2] += a.w * bv.z; acc[3][3] += a.w * bv.w;
    }
  }
  int ty = tid >> 4, tx = tid & 15;
#pragma unroll
  for (int i = 0; i < 4; ++i) {
    int m = m0 + ty * 4 + i;
#pragma unroll
    for (int j = 0; j < 4; ++j) {
      int n = n0 + tx * 4 + j;
      float v = acc[i][j] + cbias[n];
      v = bng[n] * v * BN_SC + bnb[n];
      h1[(size_t)m * 384 + n] = fmaxf(v, 0.f);
    }
  }
}

// ---------------------------------------------------------------- k_gate
__global__ __launch_bounds__(256) void k_gate(const float* h1, const float* w2, const float* b2,
                                              float* gA, float* gB) {
  __shared__ float red[8];
  int bt = blockIdx.x, tid = threadIdx.x;
  float v0 = 0.f, v1 = 0.f;
  if (tid < 192) {
    v0 = h1[(size_t)bt * 384 + tid] * w2[tid];
    v1 = h1[(size_t)bt * 384 + 192 + tid] * w2[192 + tid];
  }
  float s0 = blockSum(v0, red);
  float s1 = blockSum(v1, red);
  if (tid == 0) {
    gA[bt] = 1.f / (1.f + expf(-(s0 + b2[0])));
    gB[bt] = 1.f / (1.f + expf(-(s1 + b2[1])));
  }
}

// ---------------------------------------------------------------- k_mg (hard gates + cumprod)
__global__ __launch_bounds__(256) void k_mg(const float* gA, const float* gB, float* mg, float* mgn) {
  int idx = blockIdx.x * 256 + threadIdx.x;
  if (idx >= TB) return;
  int t = idx >> 5, b = idx & 31;
  float g = gA[b * 192 + t], gn = gB[b * 192 + t];
  float p = 1.f, pn = 1.f;
  for (int k = 0; k < 15; ++k) {
    float ghat = (k <= t) ? gA[b * 192 + t - k] : 1e9f;
    float u = fminf(fmaxf((g - ghat) / 0.1f * 2.f + 1.f, -1.f), 1.f);
    float un = fminf(fmaxf((gn - ghat) / 0.1f * 2.f + 1.f, -1.f), 1.f);
    p *= (u + 1.f) * 0.5f;
    pn *= (un + 1.f) * 0.5f;
    mg[(size_t)idx * 15 + k] = p;
    mgn[(size_t)idx * 15 + k] = pn;
  }
}

// ---------------------------------------------------------------- k_gemm (generic)
__global__ __launch_bounds__(256) void k_gemm(const float* A, int lda, const float* W, int ldw,
                                              const float* bias, float* Cf, int ldc, int K, int mode,
                                              const float* bng, const float* bnb, float* Cb) {
  __shared__ float As[32][68];
  __shared__ float Bs[32][68];
  int n0 = blockIdx.x * 64, m0 = blockIdx.y * 64;
  int tid = threadIdx.x;
  float acc[4][4] = {};
  int mi = tid >> 3, kq = tid & 7;
  int ni = tid >> 2, kb = tid & 3;
  for (int kk = 0; kk < K; kk += 32) {
    __syncthreads();
#pragma unroll
    for (int p = 0; p < 2; ++p) {
      int m = m0 + mi + 32 * p;
      float4 v = *(const float4*)(A + (size_t)m * lda + kk + kq * 4);
      As[kq * 4 + 0][mi + 32 * p] = v.x; As[kq * 4 + 1][mi + 32 * p] = v.y;
      As[kq * 4 + 2][mi + 32 * p] = v.z; As[kq * 4 + 3][mi + 32 * p] = v.w;
    }
    {
      const float* wp = W + (size_t)(n0 + ni) * ldw + kk + kb * 8;
      float4 q0 = *(const float4*)(wp);
      float4 q1 = *(const float4*)(wp + 4);
      Bs[kb * 8 + 0][ni] = q0.x; Bs[kb * 8 + 1][ni] = q0.y;
      Bs[kb * 8 + 2][ni] = q0.z; Bs[kb * 8 + 3][ni] = q0.w;
      Bs[kb * 8 + 4][ni] = q1.x; Bs[kb * 8 + 5][ni] = q1.y;
      Bs[kb * 8 + 6][ni] = q1.z; Bs[kb * 8 + 7][ni] = q1.w;
    }
    __syncthreads();
    int ty = tid >> 4, tx = tid & 15;
#pragma unroll
    for (int k = 0; k < 32; ++k) {
      float4 a = *(const float4*)(&As[k][ty * 4]);
      float4 bv = *(const float4*)(&Bs[k][tx * 4]);
      acc[0][0] += a.x * bv.x; acc[0][1] += a.x * bv.y; acc[0][2] += a.x * bv.z; acc[0][3] += a.x * bv.w;
      acc[1][0] += a.y * bv.x; acc[1][1] += a.y * bv.y; acc[1][2] += a.y * bv.z; acc[1][3] += a.y * bv.w;
      acc[2][0] += a.z * bv.x; acc[2][1] += a.z * bv.y; acc[2][2] += a.z * bv.z; acc[2][3] += a.z * bv.w;
      acc[3][0] += a.w * bv.x; acc[3][1] += a.w * bv.y; acc[3][2] += a.w * bv.z; acc[3][3] += a.w * bv.w;
    }
  }
  int ty = tid >> 4, tx = tid & 15;
#pragma unroll
  for (int i = 0; i < 4; ++i) {
    int m = m0 + ty * 4 + i;
#pragma unroll
    for (int j = 0; j < 4; ++j) {
      int n = n0 + tx * 4 + j;
      float v = acc[i][j];
      if (bias) v += bias[n];
      if (mode == 0) Cf[(size_t)m * ldc + n] = v;
      else Cb[(size_t)m * ldc + n] = tanhf(bng[n] * v * BN_SC + bnb[n]);
    }
  }
}

// ---------------------------------------------------------------- k_ln_rows
__global__ __launch_bounds__(256) void k_ln_rows(float* X, const float* g, const float* bt) {
  __shared__ float red[8];
  float* x = X + (size_t)blockIdx.x * 1536;
  int tid = threadIdx.x;
  float ps = 0.f;
  for (int i = tid; i < 1536; i += 256) ps += x[i];
  float mu = blockSum(ps, red) * (1.f / 1536.f);
  ps = 0.f;
  for (int i = tid; i < 1536; i += 256) { float d = x[i] - mu; ps += d * d; }
  float inv = 1.f / (sqrtf(blockSum(ps, red) * (1.f / 1535.f)) + 1e-6f);
  for (int i = tid; i < 1536; i += 256) x[i] = g[i] * (x[i] - mu) * inv + bt[i];
}

// ---------------------------------------------------------------- scan kernel
struct ScanArgs {
  float* ws;
  const float *r_whh, *r_bhh, *r_lnhh_g, *r_lnhh_b, *r_lnih_g, *r_lnih_b;
  const float *r_lnc_g, *r_lnc_b, *r_wih, *r_bih, *r_proj_w, *r_proj_b;
  const float *p_proj_w, *p_proj_b;
};

struct GJob { const float* W; int ldw; int koff; const float* bias; float* dst; int rstride; int ncols; };

__device__ __forceinline__ void resolveJob(const GJob* J, int col, const float*& W, int& ldw, int& koff,
                                           const float*& bias, float*& dst, int& rstride, int& cc) {
  int c = col;
#pragma unroll
  for (int j = 0; j < 4; ++j) {
    if (c < J[j].ncols) {
      W = J[j].W; ldw = J[j].ldw; koff = J[j].koff; bias = J[j].bias;
      dst = J[j].dst; rstride = J[j].rstride; cc = c; return;
    }
    c -= J[j].ncols;
  }
  W = J[0].W; ldw = J[0].ldw; koff = J[0].koff; bias = J[0].bias;
  dst = J[0].dst; rstride = J[0].rstride; cc = 0;
}

// Relaxed-atomic sense barrier. Data exchange is via sc0+sc1 (LLC) accesses,
// so no L2 writeback/invalidate is needed; __syncthreads() already drains
// vmcnt(0) so all this wg's LLC stores completed before arrival.
__device__ void grid_barrier(unsigned* bar) {
  __syncthreads();
  __atomic_signal_fence(__ATOMIC_SEQ_CST);
  if (threadIdx.x == 0) {
    unsigned gen = __hip_atomic_load(&bar[1], __ATOMIC_RELAXED, __HIP_MEMORY_SCOPE_AGENT);
    unsigned arr = __hip_atomic_fetch_add(&bar[0], 1u, __ATOMIC_RELAXED, __HIP_MEMORY_SCOPE_AGENT);
    if (arr == 127u) {
      __hip_atomic_store(&bar[0], 0u, __ATOMIC_RELAXED, __HIP_MEMORY_SCOPE_AGENT);
      __hip_atomic_store(&bar[1], gen + 1u, __ATOMIC_RELAXED, __HIP_MEMORY_SCOPE_AGENT);
    } else {
      while (__hip_atomic_load(&bar[1], __ATOMIC_RELAXED, __HIP_MEMORY_SCOPE_AGENT) == gen)
        __builtin_amdgcn_s_sleep(4);
    }
  }
  __atomic_signal_fence(__ATOMIC_SEQ_CST);
  __syncthreads();
}

// weight-shared GEMV phase: cols split over 96 wgs, K=384 split over 8 thread-groups,
// partials reduced via LDS. Weights: plain loads (L2-resident, same cols every step).
// x-vector and outputs: LLC-coherent (ldx/stx).
__device__ void gemm_phase(const float* src, const GJob* J, int NC, int gwg, float* red) {
  const int tid = threadIdx.x;
  const int b = tid & 31, cg = tid >> 5;
  const int colsPer = NC / 96;
  const int base = gwg * colsPer;
  const int k0 = cg * 48;
  float xr[48];
  const float* xp = src + b * 384 + k0;
#pragma unroll
  for (int q = 0; q < 48; ++q) xr[q] = ldx(xp + q);
#pragma unroll
  for (int ci = 0; ci < 28; ++ci) {
    if (ci >= colsPer) break;
    const float* W; int ldw, koff; const float* bias; float* dst; int rstride; int cc;
    resolveJob(J, base + ci, W, ldw, koff, bias, dst, rstride, cc);
    const float* wr = W + (size_t)cc * ldw + koff + k0;
    float a = 0.f;
#pragma unroll
    for (int q = 0; q < 12; ++q) {
      float4 w = *(const float4*)(wr + q * 4);
      a += w.x * xr[q * 4 + 0] + w.y * xr[q * 4 + 1]
         + w.z * xr[q * 4 + 2] + w.w * xr[q * 4 + 3];
    }
    red[(cg * colsPer + ci) * 32 + b] = a;
  }
  __syncthreads();
  const int pairs = colsPer * 32;
  for (int pi = tid; pi < pairs; pi += 256) {
    int ci = pi >> 5, bb = pi & 31;
    float s = 0.f;
#pragma unroll
    for (int g = 0; g < 8; ++g) s += red[(g * colsPer + ci) * 32 + bb];
    const float* W; int ldw, koff; const float* bias; float* dst; int rstride; int cc;
    resolveJob(J, base + ci, W, ldw, koff, bias, dst, rstride, cc);
    if (bias) s += bias[cc];
    stx(dst + (size_t)bb * rstride + cc, s);
  }
  __syncthreads();
}

// per-batch phase. Private state (memh/memc/P? no: P is exchanged) rules:
// memh/memc: plain (same wg always). P, KEY*, IH1RAW, HNEW*: LLC (ldx/stx).
__device__ void per_b_layer(int layer, int t, int b, const ScanArgs& A, float* sm) {
  float* ws = A.ws;
  const int tid = threadIdx.x;
  const size_t tb = (size_t)t * 32 + b;
  float* memh = ws + (layer ? O_MEMH1 : O_MEMH0) + (size_t)b * 15 * 384;
  float* memc = ws + (layer ? O_MEMC1 : O_MEMC0) + (size_t)b * 15 * 384;
  float* P = ws + (layer ? O_P1 : O_P0) + (size_t)b * 15 * 1536;
  float* keyl = sm; float* logit = sm + 384; float* att = sm + 400; float* red = sm + 416;
  float* ghh = sm + 448; float* gih = sm + 1984; float* selc = sm + 3520;
  float* cnew = sm + 3904; float* ogat = sm + 4288;

  for (int h = tid; h < 384; h += 256) {
    float k1, k2;
    if (layer == 0) { k1 = ws[O_KEY0E + tb * 384 + h]; k2 = ldx(ws + O_KEY0MH + (size_t)b * 384 + h); }
    else { k1 = ldx(ws + O_KEY1H + (size_t)b * 384 + h); k2 = ldx(ws + O_KEY1MH + (size_t)b * 384 + h); }
    keyl[h] = k1 + k2;
  }
  __syncthreads();
  {
    int s = tid >> 4, l = tid & 15;
    if (s < 15) {
      const float* mh = memh + ((t + s) % 15) * 384;
      float p = 0.f;
      for (int k = l; k < 384; k += 16) p += mh[k] * keyl[k];
      p += __shfl_down(p, 8, 64); p += __shfl_down(p, 4, 64);
      p += __shfl_down(p, 2, 64); p += __shfl_down(p, 1, 64);
      if (l == 0) logit[s] = p * INV_SQRT_H;
    }
  }
  __syncthreads();
  if (tid == 0) {
    const float* mgp = ws + O_MG + tb * 15;
    float m = logit[0];
    for (int i = 1; i < 15; ++i) m = fmaxf(m, logit[i]);
    float sum = 0.f;
    for (int i = 0; i < 15; ++i) { float e = expf(logit[i] - m) * mgp[i]; att[i] = e; sum += e; }
    float inv = 1.f / (sum + 1e-8f);
    for (int i = 0; i < 15; ++i) att[i] *= inv;
  }
  __syncthreads();
  float av[15]; int pidx[15];
#pragma unroll
  for (int i = 0; i < 15; ++i) { av[i] = att[i]; pidx[i] = (t + i) % 15; }
  const float* bhh = A.r_bhh + layer * 1536;
  for (int n = tid; n < 1536; n += 256) {
    float acc = bhh[n];
#pragma unroll
    for (int i = 0; i < 15; ++i) acc += av[i] * ldx(P + (size_t)pidx[i] * 1536 + n);
    ghh[n] = acc;
  }
  for (int h = tid; h < 384; h += 256) {
    float acc = 0.f;
#pragma unroll
    for (int i = 0; i < 15; ++i) acc += av[i] * memc[pidx[i] * 384 + h];
    selc[h] = acc;
  }
  if (layer) {
    for (int n = tid; n < 1536; n += 256) gih[n] = ldx(ws + O_IH1RAW + (size_t)b * 1536 + n);
  }
  __syncthreads();
  float ps = 0.f;
  for (int n = tid; n < 1536; n += 256) ps += ghh[n];
  float mu_hh = blockSum(ps, red) * (1.f / 1536.f);
  ps = 0.f;
  for (int n = tid; n < 1536; n += 256) { float d = ghh[n] - mu_hh; ps += d * d; }
  float inv_hh = 1.f / (sqrtf(blockSum(ps, red) * (1.f / 1535.f)) + 1e-6f);
  float mu_ih = 0.f, inv_ih = 0.f;
  if (layer) {
    ps = 0.f;
    for (int n = tid; n < 1536; n += 256) ps += gih[n];
    mu_ih = blockSum(ps, red) * (1.f / 1536.f);
    ps = 0.f;
    for (int n = tid; n < 1536; n += 256) { float d = gih[n] - mu_ih; ps += d * d; }
    inv_ih = 1.f / (sqrtf(blockSum(ps, red) * (1.f / 1535.f)) + 1e-6f);
  }
  const float *hg = A.r_lnhh_g + layer * 1536, *hb = A.r_lnhh_b + layer * 1536;
  const float *ig = A.r_lnih_g + 1536, *ib = A.r_lnih_b + 1536;
  for (int h = tid; h < 384; h += 256) {
    float gi, gf, gc, go;
    if (layer == 0) {
      const float* ihr = ws + O_IH0LN + tb * 1536;
      gi = ihr[h]; gf = ihr[384 + h]; gc = ihr[768 + h]; go = ihr[1152 + h];
    } else {
      gi = ig[h] * (gih[h] - mu_ih) * inv_ih + ib[h];
      gf = ig[384 + h] * (gih[384 + h] - mu_ih) * inv_ih + ib[384 + h];
      gc = ig[768 + h] * (gih[768 + h] - mu_ih) * inv_ih + ib[768 + h];
      go = ig[1152 + h] * (gih[1152 + h] - mu_ih) * inv_ih + ib[1152 + h];
    }
    gi += hg[h] * (ghh[h] - mu_hh) * inv_hh + hb[h];
    gf += hg[384 + h] * (ghh[384 + h] - mu_hh) * inv_hh + hb[384 + h];
    gc += hg[768 + h] * (ghh[768 + h] - mu_hh) * inv_hh + hb[768 + h];
    go += hg[1152 + h] * (ghh[1152 + h] - mu_hh) * inv_hh + hb[1152 + h];
    float c = sigmoidf(gf) * selc[h] + sigmoidf(gi) * tanhf(gc);
    cnew[h] = c; ogat[h] = go;
  }
  __syncthreads();
  ps = 0.f;
  for (int h = tid; h < 384; h += 256) ps += cnew[h];
  float mu_c = blockSum(ps, red) * (1.f / 384.f);
  ps = 0.f;
  for (int h = tid; h < 384; h += 256) { float d = cnew[h] - mu_c; ps += d * d; }
  float inv_c = 1.f / (sqrtf(blockSum(ps, red) * (1.f / 383.f)) + 1e-6f);
  const float *lcg = A.r_lnc_g + layer * 384, *lcb = A.r_lnc_b + layer * 384;
  const int slot = t % 15;
  for (int h = tid; h < 384; h += 256) {
    float hn = sigmoidf(ogat[h]) * tanhf(lcg[h] * (cnew[h] - mu_c) * inv_c + lcb[h]);
    memh[slot * 384 + h] = hn;
    memc[slot * 384 + h] = cnew[h];
    if (layer == 0) stx(ws + O_HNEW0 + (size_t)b * 384 + h, hn);
    else { stx(ws + O_HNEW1 + (size_t)b * 384 + h, hn); ws[O_OUTHS + tb * 768 + h] = hn; }
  }
}

__device__ void per_b_predict(int tau, int b, const ScanArgs& A, float* sm) {
  float* ws = A.ws;
  const int tid = threadIdx.x;
  const size_t tb = (size_t)tau * 32 + b;
  float* pmem = ws + O_PMEM + (size_t)b * 15 * 384;
  float* keyl = sm; float* logit = sm + 384; float* att = sm + 400;
  for (int h = tid; h < 384; h += 256)
    keyl[h] = ldx(ws + O_PKEYH + (size_t)b * 384 + h)
            + ldx(ws + O_PKEYMH + (size_t)(tau & 1) * 12288 + (size_t)b * 384 + h);
  __syncthreads();
  {
    int s = tid >> 4, l = tid & 15;
    if (s < 15) {
      const float* mh = pmem + ((tau + s) % 15) * 384;
      float p = 0.f;
      for (int k = l; k < 384; k += 16) p += mh[k] * keyl[k];
      p += __shfl_down(p, 8, 64); p += __shfl_down(p, 4, 64);
      p += __shfl_down(p, 2, 64); p += __shfl_down(p, 1, 64);
      if (l == 0) logit[s] = p * INV_SQRT_H;
    }
  }
  __syncthreads();
  if (tid == 0) {
    const float* mgp = ws + O_MGN + tb * 15;
    float m = logit[0];
    for (int i = 1; i < 15; ++i) m = fmaxf(m, logit[i]);
    float sum = 0.f;
    for (int i = 0; i < 15; ++i) { float e = expf(logit[i] - m) * mgp[i]; att[i] = e; sum += e; }
    float inv = 1.f / (sum + 1e-8f);
    for (int i = 0; i < 15; ++i) att[i] *= inv;
  }
  __syncthreads();
  float av[15]; int pidx[15];
#pragma unroll
  for (int i = 0; i < 15; ++i) { av[i] = att[i]; pidx[i] = (tau + i) % 15; }
  for (int h = tid; h < 384; h += 256) {
    float acc = 0.f;
#pragma unroll
    for (int i = 0; i < 15; ++i) acc += av[i] * pmem[pidx[i] * 384 + h];
    ws[O_OUTHS + tb * 768 + 384 + h] = acc;
  }
  __syncthreads();  // all pmem reads done before append overwrites oldest slot
  for (int h = tid; h < 384; h += 256)
    pmem[(tau % 15) * 384 + h] = ldx(ws + O_HNEW1 + (size_t)b * 384 + h);
}

__global__ __launch_bounds__(256) void k_scan(ScanArgs A) {
  __shared__ float sm[7424];
  float* ws = A.ws;
  unsigned* bar = (unsigned*)(ws + O_BAR);
  const int wg = blockIdx.x;
  for (int t = 0; t <= TT; ++t) {
    // ---- Phase 1: per-b layer0 | GEMVs from h_new1(t-1) ----
    if (wg < 32) {
      if (t < TT) per_b_layer(0, t, wg, A, sm);
    } else {
      GJob J[4] = {
        { A.r_whh + 589824, 384, 0, nullptr, ws + O_P1 + (size_t)((t + 14) % 15) * 1536, 23040, 1536 },
        { A.r_proj_w + 294912, 768, 384, nullptr, ws + O_KEY1MH, 384, 384 },
        { A.p_proj_w, 768, 0, A.p_proj_b, ws + O_PKEYH, 384, 384 },
        { A.p_proj_w, 768, 384, nullptr, ws + O_PKEYMH + (size_t)(t & 1) * 12288, 384, 384 },
      };
      gemm_phase(ws + O_HNEW1, J, 2688, wg - 32, sm);
    }
    grid_barrier(bar);
    // ---- Phase 2: per-b predict-att(t-1) | GEMVs from h_new0(t) ----
    if (wg < 32) {
      if (t >= 1) per_b_predict(t - 1, wg, A, sm);
    } else if (t < TT) {
      GJob J[4] = {
        { A.r_wih + 589824, 384, 0, A.r_bih + 1536, ws + O_IH1RAW, 1536, 1536 },
        { A.r_proj_w + 294912, 768, 0, A.r_proj_b + 384, ws + O_KEY1H, 384, 384 },
        { nullptr, 0, 0, nullptr, nullptr, 0, 0 },
        { nullptr, 0, 0, nullptr, nullptr, 0, 0 },
      };
      gemm_phase(ws + O_HNEW0, J, 1920, wg - 32, sm);
    }
    if (t == TT) break;
    grid_barrier(bar);
    // ---- Phase 3: per-b layer1 | GEMVs from h_new0(t) for next step ----
    if (wg < 32) {
      per_b_layer(1, t, wg, A, sm);
    } else {
      GJob J[4] = {
        { A.r_whh, 384, 0, nullptr, ws + O_P0 + (size_t)(t % 15) * 1536, 23040, 1536 },
        { A.r_proj_w, 768, 384, nullptr, ws + O_KEY0MH, 384, 384 },
        { nullptr, 0, 0, nullptr, nullptr, 0, 0 },
        { nullptr, 0, 0, nullptr, nullptr, 0, 0 },
      };
      gemm_phase(ws + O_HNEW0, J, 1920, wg - 32, sm);
    }
    grid_barrier(bar);
  }
}

// ---------------------------------------------------------------- launch
extern "C" void kernel_launch(void* const* d_in, const int* in_sizes, int n_in,
                              void* d_out, int out_size, void* d_ws, size_t ws_size,
                              hipStream_t stream) {
  const int* ids = (const int*)d_in[0];
  const float* emb_w = (const float*)d_in[1];
  const float* pconv1_w = (const float*)d_in[2];
  const float* pconv1_b = (const float*)d_in[3];
  const float* pbn_g = (const float*)d_in[4];
  const float* pbn_b = (const float*)d_in[5];
  const float* pconv2_w = (const float*)d_in[6];
  const float* pconv2_b = (const float*)d_in[7];
  const float* r_wih = (const float*)d_in[8];
  const float* r_bih = (const float*)d_in[9];
  const float* r_whh = (const float*)d_in[10];
  const float* r_bhh = (const float*)d_in[11];
  const float* r_lnih_g = (const float*)d_in[12];
  const float* r_lnih_b = (const float*)d_in[13];
  const float* r_lnhh_g = (const float*)d_in[14];
  const float* r_lnhh_b = (const float*)d_in[15];
  const float* r_lnc_g = (const float*)d_in[16];
  const float* r_lnc_b = (const float*)d_in[17];
  const float* r_proj_w = (const float*)d_in[18];
  const float* r_proj_b = (const float*)d_in[19];
  const float* p_proj_w = (const float*)d_in[20];
  const float* p_proj_b = (const float*)d_in[21];
  const float* p_ffd_w = (const float*)d_in[22];
  const float* p_ffd_b = (const float*)d_in[23];
  const float* p_bn_g = (const float*)d_in[24];
  const float* p_bn_b = (const float*)d_in[25];
  float* ws = (float*)d_ws;
  float* out = (float*)d_out;

  k_zero<<<1024, 256, 0, stream>>>(ws + O_MEMH0, (int)(O_WSEND - O_MEMH0));
  k_emb<<<4096, 256, 0, stream>>>(ids, emb_w, ws + O_EMB, out);
  k_conv<<<dim3(6, 96), 256, 0, stream>>>(ws + O_EMB, pconv1_w, pconv1_b, pbn_g, pbn_b, ws + O_H1);
  k_gate<<<6144, 256, 0, stream>>>(ws + O_H1, pconv2_w, pconv2_b, ws + O_GATEA, ws + O_GATEB);
  k_mg<<<24, 256, 0, stream>>>(ws + O_GATEA, ws + O_GATEB, ws + O_MG, ws + O_MGN);
  // precompute LN(e@Wih0+b) and key0_e = e@proj0_h + b for all t
  k_gemm<<<dim3(24, 96), 256, 0, stream>>>(ws + O_EMB, 384, r_wih, 384, r_bih,
                                           ws + O_IH0LN, 1536, 384, 0, nullptr, nullptr, nullptr);
  k_gemm<<<dim3(6, 96), 256, 0, stream>>>(ws + O_EMB, 384, r_proj_w, 768, r_proj_b,
                                          ws + O_KEY0E, 384, 384, 0, nullptr, nullptr, nullptr);
  k_ln_rows<<<6144, 256, 0, stream>>>(ws + O_IH0LN, r_lnih_g, r_lnih_b);
  ScanArgs SA{ws, r_whh, r_bhh, r_lnhh_g, r_lnhh_b, r_lnih_g, r_lnih_b,
              r_lnc_g, r_lnc_b, r_wih, r_bih, r_proj_w, r_proj_b, p_proj_w, p_proj_b};
  k_scan<<<128, 256, 0, stream>>>(SA);
  // head: y = tanh(BN(flat @ p_ffd^T + b)) -> out
  k_gemm<<<dim3(6, 96), 256, 0, stream>>>(ws + O_OUTHS, 768, p_ffd_w, 768, p_ffd_b,
                                          nullptr, 384, 768, 1, p_bn_g, p_bn_b, out);
}

// Round 4
// 15148.009 us; speedup vs baseline: 2.2314x; 1.6679x over previous
//
#include <hip/hip_runtime.h>

// PRPN eval forward for MI355X. All float inputs are FP32, ids int32.
// Output = [y (T*B*D) | mask (T*B)] fp32.
//
// R4 vs R3: the flat 128-way single-cacheline barrier (poll storm saturated
// one LLC slice -> ~43us/phase) is replaced by a hierarchical 8x16 barrier
// with 64B-padded monotone counters (no resets -> all-relaxed safe; <=15
// pollers/line). GEMV final stores reordered for line coalescing.

#define TT 192
#define TB 6144

constexpr size_t O_EMB    = 0;          // T*B*384 fp32
constexpr size_t O_IH0LN  = 2359296;    // T*B*1536 (raw then LN'd in place)
constexpr size_t O_KEY0E  = 11796480;   // T*B*384
constexpr size_t O_MG     = 14155776;   // T*B*15
constexpr size_t O_MGN    = 14247936;   // T*B*15
constexpr size_t O_H1     = 14340096;   // B*T x 384 (conv activations, b-major rows)
constexpr size_t O_GATEA  = 16699392;   // B*T
constexpr size_t O_GATEB  = 16705536;   // B*T
constexpr size_t O_OUTHS  = 16711680;   // T*B x 768 (h | sel)
constexpr size_t O_MEMH0  = 21430272;   // state (zeroed): B x 15 x 384 each
constexpr size_t O_MEMC0  = 21614592;
constexpr size_t O_MEMH1  = 21798912;
constexpr size_t O_MEMC1  = 21983232;
constexpr size_t O_PMEM   = 22167552;
constexpr size_t O_P0     = 22351872;   // B x 15 x 1536
constexpr size_t O_P1     = 23089152;
constexpr size_t O_HNEW0  = 23826432;   // B x 384
constexpr size_t O_HNEW1  = 23838720;
constexpr size_t O_IH1RAW = 23851008;   // B x 1536
constexpr size_t O_KEY1H  = 23900160;
constexpr size_t O_KEY0MH = 23912448;
constexpr size_t O_KEY1MH = 23924736;
constexpr size_t O_PKEYH  = 23937024;
constexpr size_t O_PKEYMH = 23949312;   // 2 x B x 384 (ping-pong)
constexpr size_t O_BAR    = 23973888;   // barrier counters (288 u32, 64B padded)
constexpr size_t O_WSEND  = 23974176;

__device__ __forceinline__ float sigmoidf(float x) { return 1.f / (1.f + expf(-x)); }

// LLC-coherent (bypass per-XCD L2) relaxed accessors for cross-wg exchange.
__device__ __forceinline__ float ldx(const float* p) {
  return __hip_atomic_load(p, __ATOMIC_RELAXED, __HIP_MEMORY_SCOPE_AGENT);
}
__device__ __forceinline__ void stx(float* p, float v) {
  __hip_atomic_store(p, v, __ATOMIC_RELAXED, __HIP_MEMORY_SCOPE_AGENT);
}
__device__ __forceinline__ unsigned ldu(const unsigned* p) {
  return __hip_atomic_load(p, __ATOMIC_RELAXED, __HIP_MEMORY_SCOPE_AGENT);
}

constexpr float BN_SC = 0.9999950000374997f;       // 1/sqrt(1+1e-5)
constexpr float INV_SQRT_H = 0.05103103630798288f; // 1/sqrt(384)

__device__ __forceinline__ float blockSum(float v, float* red) {
#pragma unroll
  for (int off = 32; off > 0; off >>= 1) v += __shfl_down(v, off, 64);
  __syncthreads();
  if ((threadIdx.x & 63) == 0) red[threadIdx.x >> 6] = v;
  __syncthreads();
  return red[0] + red[1] + red[2] + red[3];
}

// ---------------------------------------------------------------- k_zero
__global__ __launch_bounds__(256) void k_zero(float* p, int n) {
  int i = blockIdx.x * 256 + threadIdx.x;
  int stride = gridDim.x * 256;
  for (; i < n; i += stride) p[i] = 0.f;
}

// ---------------------------------------------------------------- k_emb (+mask)
__global__ __launch_bounds__(256) void k_emb(const int* ids, const float* emb_w,
                                             float* emb, float* out) {
  size_t idx = (size_t)blockIdx.x * 256 + threadIdx.x;
  size_t stride = (size_t)gridDim.x * 256;
  for (size_t i = idx; i < (size_t)TB * 384; i += stride) {
    size_t tb = i / 384, d = i - tb * 384;
    int id = ids[tb];
    emb[i] = emb_w[(size_t)id * 384 + d];
    if (i < TB) out[(size_t)TB * 384 + i] = (ids[i] != 0) ? 1.f : 0.f;
  }
}

// ---------------------------------------------------------------- k_conv (im2col GEMM)
__global__ __launch_bounds__(256) void k_conv(const float* emb, const float* W1, const float* cbias,
                                              const float* bng, const float* bnb, float* h1) {
  __shared__ float As[32][68];
  __shared__ float Bs[32][68];
  int n0 = blockIdx.x * 64, m0 = blockIdx.y * 64;
  int tid = threadIdx.x;
  float acc[4][4] = {};
  int mi = tid >> 3, kq = tid & 7;
  int ni = tid >> 2, kb = tid & 3;
  for (int kk = 0; kk < 2304; kk += 32) {
    int kc = kk / 384, dbase = kk - kc * 384;
    __syncthreads();
#pragma unroll
    for (int p = 0; p < 2; ++p) {
      int m = m0 + mi + 32 * p;
      int b = m / 192, t = m - b * 192;
      int tt = t + kc - 5;
      float4 v = {0.f, 0.f, 0.f, 0.f};
      if (tt >= 0) v = *(const float4*)(emb + ((size_t)tt * 32 + b) * 384 + dbase + kq * 4);
      As[kq * 4 + 0][mi + 32 * p] = v.x; As[kq * 4 + 1][mi + 32 * p] = v.y;
      As[kq * 4 + 2][mi + 32 * p] = v.z; As[kq * 4 + 3][mi + 32 * p] = v.w;
    }
#pragma unroll
    for (int i = 0; i < 8; ++i) {
      int d = dbase + kb * 8 + i;
      Bs[kb * 8 + i][ni] = W1[(size_t)(n0 + ni) * 2304 + d * 6 + kc];
    }
    __syncthreads();
    int ty = tid >> 4, tx = tid & 15;
#pragma unroll
    for (int k = 0; k < 32; ++k) {
      float4 a = *(const float4*)(&As[k][ty * 4]);
      float4 bv = *(const float4*)(&Bs[k][tx * 4]);
      acc[0][0] += a.x * bv.x; acc[0][1] += a.x * bv.y; acc[0][2] += a.x * bv.z; acc[0][3] += a.x * bv.w;
      acc[1][0] += a.y * bv.x; acc[1][1] += a.y * bv.y; acc[1][2] += a.y * bv.z; acc[1][3] += a.y * bv.w;
      acc[2][0] += a.z * bv.x; acc[2][1] += a.z * bv.y; acc[2][2] += a.z * bv.z; acc[2][3] += a.z * bv.w;
      acc[3][0] += a.w * bv.x; acc[3][1] += a.w * bv.y; acc[3][2] += a.w * bv.z; acc[3][3] += a.w * bv.w;
    }
  }
  int ty = tid >> 4, tx = tid & 15;
#pragma unroll
  for (int i = 0; i < 4; ++i) {
    int m = m0 + ty * 4 + i;
#pragma unroll
    for (int j = 0; j < 4; ++j) {
      int n = n0 + tx * 4 + j;
      float v = acc[i][j] + cbias[n];
      v = bng[n] * v * BN_SC + bnb[n];
      h1[(size_t)m * 384 + n] = fmaxf(v, 0.f);
    }
  }
}

// ---------------------------------------------------------------- k_gate
__global__ __launch_bounds__(256) void k_gate(const float* h1, const float* w2, const float* b2,
                                              float* gA, float* gB) {
  __shared__ float red[8];
  int bt = blockIdx.x, tid = threadIdx.x;
  float v0 = 0.f, v1 = 0.f;
  if (tid < 192) {
    v0 = h1[(size_t)bt * 384 + tid] * w2[tid];
    v1 = h1[(size_t)bt * 384 + 192 + tid] * w2[192 + tid];
  }
  float s0 = blockSum(v0, red);
  float s1 = blockSum(v1, red);
  if (tid == 0) {
    gA[bt] = 1.f / (1.f + expf(-(s0 + b2[0])));
    gB[bt] = 1.f / (1.f + expf(-(s1 + b2[1])));
  }
}

// ---------------------------------------------------------------- k_mg (hard gates + cumprod)
__global__ __launch_bounds__(256) void k_mg(const float* gA, const float* gB, float* mg, float* mgn) {
  int idx = blockIdx.x * 256 + threadIdx.x;
  if (idx >= TB) return;
  int t = idx >> 5, b = idx & 31;
  float g = gA[b * 192 + t], gn = gB[b * 192 + t];
  float p = 1.f, pn = 1.f;
  for (int k = 0; k < 15; ++k) {
    float ghat = (k <= t) ? gA[b * 192 + t - k] : 1e9f;
    float u = fminf(fmaxf((g - ghat) / 0.1f * 2.f + 1.f, -1.f), 1.f);
    float un = fminf(fmaxf((gn - ghat) / 0.1f * 2.f + 1.f, -1.f), 1.f);
    p *= (u + 1.f) * 0.5f;
    pn *= (un + 1.f) * 0.5f;
    mg[(size_t)idx * 15 + k] = p;
    mgn[(size_t)idx * 15 + k] = pn;
  }
}

// ---------------------------------------------------------------- k_gemm (generic)
__global__ __launch_bounds__(256) void k_gemm(const float* A, int lda, const float* W, int ldw,
                                              const float* bias, float* Cf, int ldc, int K, int mode,
                                              const float* bng, const float* bnb, float* Cb) {
  __shared__ float As[32][68];
  __shared__ float Bs[32][68];
  int n0 = blockIdx.x * 64, m0 = blockIdx.y * 64;
  int tid = threadIdx.x;
  float acc[4][4] = {};
  int mi = tid >> 3, kq = tid & 7;
  int ni = tid >> 2, kb = tid & 3;
  for (int kk = 0; kk < K; kk += 32) {
    __syncthreads();
#pragma unroll
    for (int p = 0; p < 2; ++p) {
      int m = m0 + mi + 32 * p;
      float4 v = *(const float4*)(A + (size_t)m * lda + kk + kq * 4);
      As[kq * 4 + 0][mi + 32 * p] = v.x; As[kq * 4 + 1][mi + 32 * p] = v.y;
      As[kq * 4 + 2][mi + 32 * p] = v.z; As[kq * 4 + 3][mi + 32 * p] = v.w;
    }
    {
      const float* wp = W + (size_t)(n0 + ni) * ldw + kk + kb * 8;
      float4 q0 = *(const float4*)(wp);
      float4 q1 = *(const float4*)(wp + 4);
      Bs[kb * 8 + 0][ni] = q0.x; Bs[kb * 8 + 1][ni] = q0.y;
      Bs[kb * 8 + 2][ni] = q0.z; Bs[kb * 8 + 3][ni] = q0.w;
      Bs[kb * 8 + 4][ni] = q1.x; Bs[kb * 8 + 5][ni] = q1.y;
      Bs[kb * 8 + 6][ni] = q1.z; Bs[kb * 8 + 7][ni] = q1.w;
    }
    __syncthreads();
    int ty = tid >> 4, tx = tid & 15;
#pragma unroll
    for (int k = 0; k < 32; ++k) {
      float4 a = *(const float4*)(&As[k][ty * 4]);
      float4 bv = *(const float4*)(&Bs[k][tx * 4]);
      acc[0][0] += a.x * bv.x; acc[0][1] += a.x * bv.y; acc[0][2] += a.x * bv.z; acc[0][3] += a.x * bv.w;
      acc[1][0] += a.y * bv.x; acc[1][1] += a.y * bv.y; acc[1][2] += a.y * bv.z; acc[1][3] += a.y * bv.w;
      acc[2][0] += a.z * bv.x; acc[2][1] += a.z * bv.y; acc[2][2] += a.z * bv.z; acc[2][3] += a.z * bv.w;
      acc[3][0] += a.w * bv.x; acc[3][1] += a.w * bv.y; acc[3][2] += a.w * bv.z; acc[3][3] += a.w * bv.w;
    }
  }
  int ty = tid >> 4, tx = tid & 15;
#pragma unroll
  for (int i = 0; i < 4; ++i) {
    int m = m0 + ty * 4 + i;
#pragma unroll
    for (int j = 0; j < 4; ++j) {
      int n = n0 + tx * 4 + j;
      float v = acc[i][j];
      if (bias) v += bias[n];
      if (mode == 0) Cf[(size_t)m * ldc + n] = v;
      else Cb[(size_t)m * ldc + n] = tanhf(bng[n] * v * BN_SC + bnb[n]);
    }
  }
}

// ---------------------------------------------------------------- k_ln_rows
__global__ __launch_bounds__(256) void k_ln_rows(float* X, const float* g, const float* bt) {
  __shared__ float red[8];
  float* x = X + (size_t)blockIdx.x * 1536;
  int tid = threadIdx.x;
  float ps = 0.f;
  for (int i = tid; i < 1536; i += 256) ps += x[i];
  float mu = blockSum(ps, red) * (1.f / 1536.f);
  ps = 0.f;
  for (int i = tid; i < 1536; i += 256) { float d = x[i] - mu; ps += d * d; }
  float inv = 1.f / (sqrtf(blockSum(ps, red) * (1.f / 1535.f)) + 1e-6f);
  for (int i = tid; i < 1536; i += 256) x[i] = g[i] * (x[i] - mu) * inv + bt[i];
}

// ---------------------------------------------------------------- scan kernel
struct ScanArgs {
  float* ws;
  const float *r_whh, *r_bhh, *r_lnhh_g, *r_lnhh_b, *r_lnih_g, *r_lnih_b;
  const float *r_lnc_g, *r_lnc_b, *r_wih, *r_bih, *r_proj_w, *r_proj_b;
  const float *p_proj_w, *p_proj_b;
};

struct GJob { const float* W; int ldw; int koff; const float* bias; float* dst; int rstride; int ncols; };

__device__ __forceinline__ void resolveJob(const GJob* J, int col, const float*& W, int& ldw, int& koff,
                                           const float*& bias, float*& dst, int& rstride, int& cc) {
  int c = col;
#pragma unroll
  for (int j = 0; j < 4; ++j) {
    if (c < J[j].ncols) {
      W = J[j].W; ldw = J[j].ldw; koff = J[j].koff; bias = J[j].bias;
      dst = J[j].dst; rstride = J[j].rstride; cc = c; return;
    }
    c -= J[j].ncols;
  }
  W = J[0].W; ldw = J[0].ldw; koff = J[0].koff; bias = J[0].bias;
  dst = J[0].dst; rstride = J[0].rstride; cc = 0;
}

// Hierarchical monotone-counter barrier: 8 groups x 16 wgs, all counters on
// separate 64B lines, everything relaxed (monotone counters -> no reset race).
// k = per-wg barrier index (identical across wgs by construction).
// Layout (u32 idx): grp_cnt[g]=g*16, root_cnt=128, root_gen=144, grp_gen[g]=160+g*16.
__device__ void grid_barrier(unsigned* bar, int wg, unsigned k) {
  __syncthreads();
  if (threadIdx.x == 0) {
    const int g = wg >> 4;
    unsigned arr = __hip_atomic_fetch_add(bar + g * 16, 1u, __ATOMIC_RELAXED, __HIP_MEMORY_SCOPE_AGENT);
    if (arr == k * 16u + 15u) {                       // group leader
      unsigned ra = __hip_atomic_fetch_add(bar + 128, 1u, __ATOMIC_RELAXED, __HIP_MEMORY_SCOPE_AGENT);
      if (ra == k * 8u + 7u) {
        __hip_atomic_store(bar + 144, k + 1u, __ATOMIC_RELAXED, __HIP_MEMORY_SCOPE_AGENT);
      } else {
        while (ldu(bar + 144) < k + 1u) __builtin_amdgcn_s_sleep(2);
      }
      __hip_atomic_store(bar + 160 + g * 16, k + 1u, __ATOMIC_RELAXED, __HIP_MEMORY_SCOPE_AGENT);
    } else {
      while (ldu(bar + 160 + g * 16) < k + 1u) __builtin_amdgcn_s_sleep(8);
    }
  }
  __syncthreads();
}

// weight-shared GEMV phase: cols split over 96 wgs, K=384 split over 8 thread-groups,
// partials reduced via LDS. Weights: plain loads (L2-resident). x and outputs: LLC.
__device__ void gemm_phase(const float* src, const GJob* J, int NC, int gwg, float* red) {
  const int tid = threadIdx.x;
  const int b = tid & 31, cg = tid >> 5;
  const int colsPer = NC / 96;
  const int base = gwg * colsPer;
  const int k0 = cg * 48;
  float xr[48];
  const float* xp = src + b * 384 + k0;
#pragma unroll
  for (int q = 0; q < 48; ++q) xr[q] = ldx(xp + q);
#pragma unroll
  for (int ci = 0; ci < 28; ++ci) {
    if (ci >= colsPer) break;
    const float* W; int ldw, koff; const float* bias; float* dst; int rstride; int cc;
    resolveJob(J, base + ci, W, ldw, koff, bias, dst, rstride, cc);
    const float* wr = W + (size_t)cc * ldw + koff + k0;
    float a = 0.f;
#pragma unroll
    for (int q = 0; q < 12; ++q) {
      float4 w = *(const float4*)(wr + q * 4);
      a += w.x * xr[q * 4 + 0] + w.y * xr[q * 4 + 1]
         + w.z * xr[q * 4 + 2] + w.w * xr[q * 4 + 3];
    }
    red[(cg * colsPer + ci) * 32 + b] = a;
  }
  __syncthreads();
  const int pairs = colsPer * 32;
  // coalesced: consecutive lanes -> consecutive cc of the same output row
  for (int pi = tid; pi < pairs; pi += 256) {
    int bb = pi / colsPer, ci = pi - bb * colsPer;
    float s = 0.f;
#pragma unroll
    for (int g = 0; g < 8; ++g) s += red[(g * colsPer + ci) * 32 + bb];
    const float* W; int ldw, koff; const float* bias; float* dst; int rstride; int cc;
    resolveJob(J, base + ci, W, ldw, koff, bias, dst, rstride, cc);
    if (bias) s += bias[cc];
    stx(dst + (size_t)bb * rstride + cc, s);
  }
  __syncthreads();
}

// per-batch phase: attention (msoftmax with hard gate), P-cache combine,
// LayerNorms, LSTM cell, LN(c), memory append.
__device__ void per_b_layer(int layer, int t, int b, const ScanArgs& A, float* sm) {
  float* ws = A.ws;
  const int tid = threadIdx.x;
  const size_t tb = (size_t)t * 32 + b;
  float* memh = ws + (layer ? O_MEMH1 : O_MEMH0) + (size_t)b * 15 * 384;
  float* memc = ws + (layer ? O_MEMC1 : O_MEMC0) + (size_t)b * 15 * 384;
  float* P = ws + (layer ? O_P1 : O_P0) + (size_t)b * 15 * 1536;
  float* keyl = sm; float* logit = sm + 384; float* att = sm + 400; float* red = sm + 416;
  float* ghh = sm + 448; float* gih = sm + 1984; float* selc = sm + 3520;
  float* cnew = sm + 3904; float* ogat = sm + 4288;

  for (int h = tid; h < 384; h += 256) {
    float k1, k2;
    if (layer == 0) { k1 = ws[O_KEY0E + tb * 384 + h]; k2 = ldx(ws + O_KEY0MH + (size_t)b * 384 + h); }
    else { k1 = ldx(ws + O_KEY1H + (size_t)b * 384 + h); k2 = ldx(ws + O_KEY1MH + (size_t)b * 384 + h); }
    keyl[h] = k1 + k2;
  }
  __syncthreads();
  {
    int s = tid >> 4, l = tid & 15;
    if (s < 15) {
      const float* mh = memh + ((t + s) % 15) * 384;
      float p = 0.f;
      for (int k = l; k < 384; k += 16) p += mh[k] * keyl[k];
      p += __shfl_down(p, 8, 64); p += __shfl_down(p, 4, 64);
      p += __shfl_down(p, 2, 64); p += __shfl_down(p, 1, 64);
      if (l == 0) logit[s] = p * INV_SQRT_H;
    }
  }
  __syncthreads();
  if (tid == 0) {
    const float* mgp = ws + O_MG + tb * 15;
    float m = logit[0];
    for (int i = 1; i < 15; ++i) m = fmaxf(m, logit[i]);
    float sum = 0.f;
    for (int i = 0; i < 15; ++i) { float e = expf(logit[i] - m) * mgp[i]; att[i] = e; sum += e; }
    float inv = 1.f / (sum + 1e-8f);
    for (int i = 0; i < 15; ++i) att[i] *= inv;
  }
  __syncthreads();
  float av[15]; int pidx[15];
#pragma unroll
  for (int i = 0; i < 15; ++i) { av[i] = att[i]; pidx[i] = (t + i) % 15; }
  const float* bhh = A.r_bhh + layer * 1536;
  for (int n = tid; n < 1536; n += 256) {
    float acc = bhh[n];
#pragma unroll
    for (int i = 0; i < 15; ++i) acc += av[i] * ldx(P + (size_t)pidx[i] * 1536 + n);
    ghh[n] = acc;
  }
  for (int h = tid; h < 384; h += 256) {
    float acc = 0.f;
#pragma unroll
    for (int i = 0; i < 15; ++i) acc += av[i] * memc[pidx[i] * 384 + h];
    selc[h] = acc;
  }
  if (layer) {
    for (int n = tid; n < 1536; n += 256) gih[n] = ldx(ws + O_IH1RAW + (size_t)b * 1536 + n);
  }
  __syncthreads();
  float ps = 0.f;
  for (int n = tid; n < 1536; n += 256) ps += ghh[n];
  float mu_hh = blockSum(ps, red) * (1.f / 1536.f);
  ps = 0.f;
  for (int n = tid; n < 1536; n += 256) { float d = ghh[n] - mu_hh; ps += d * d; }
  float inv_hh = 1.f / (sqrtf(blockSum(ps, red) * (1.f / 1535.f)) + 1e-6f);
  float mu_ih = 0.f, inv_ih = 0.f;
  if (layer) {
    ps = 0.f;
    for (int n = tid; n < 1536; n += 256) ps += gih[n];
    mu_ih = blockSum(ps, red) * (1.f / 1536.f);
    ps = 0.f;
    for (int n = tid; n < 1536; n += 256) { float d = gih[n] - mu_ih; ps += d * d; }
    inv_ih = 1.f / (sqrtf(blockSum(ps, red) * (1.f / 1535.f)) + 1e-6f);
  }
  const float *hg = A.r_lnhh_g + layer * 1536, *hb = A.r_lnhh_b + layer * 1536;
  const float *ig = A.r_lnih_g + 1536, *ib = A.r_lnih_b + 1536;
  for (int h = tid; h < 384; h += 256) {
    float gi, gf, gc, go;
    if (layer == 0) {
      const float* ihr = ws + O_IH0LN + tb * 1536;
      gi = ihr[h]; gf = ihr[384 + h]; gc = ihr[768 + h]; go = ihr[1152 + h];
    } else {
      gi = ig[h] * (gih[h] - mu_ih) * inv_ih + ib[h];
      gf = ig[384 + h] * (gih[384 + h] - mu_ih) * inv_ih + ib[384 + h];
      gc = ig[768 + h] * (gih[768 + h] - mu_ih) * inv_ih + ib[768 + h];
      go = ig[1152 + h] * (gih[1152 + h] - mu_ih) * inv_ih + ib[1152 + h];
    }
    gi += hg[h] * (ghh[h] - mu_hh) * inv_hh + hb[h];
    gf += hg[384 + h] * (ghh[384 + h] - mu_hh) * inv_hh + hb[384 + h];
    gc += hg[768 + h] * (ghh[768 + h] - mu_hh) * inv_hh + hb[768 + h];
    go += hg[1152 + h] * (ghh[1152 + h] - mu_hh) * inv_hh + hb[1152 + h];
    float c = sigmoidf(gf) * selc[h] + sigmoidf(gi) * tanhf(gc);
    cnew[h] = c; ogat[h] = go;
  }
  __syncthreads();
  ps = 0.f;
  for (int h = tid; h < 384; h += 256) ps += cnew[h];
  float mu_c = blockSum(ps, red) * (1.f / 384.f);
  ps = 0.f;
  for (int h = tid; h < 384; h += 256) { float d = cnew[h] - mu_c; ps += d * d; }
  float inv_c = 1.f / (sqrtf(blockSum(ps, red) * (1.f / 383.f)) + 1e-6f);
  const float *lcg = A.r_lnc_g + layer * 384, *lcb = A.r_lnc_b + layer * 384;
  const int slot = t % 15;
  for (int h = tid; h < 384; h += 256) {
    float hn = sigmoidf(ogat[h]) * tanhf(lcg[h] * (cnew[h] - mu_c) * inv_c + lcb[h]);
    memh[slot * 384 + h] = hn;
    memc[slot * 384 + h] = cnew[h];
    if (layer == 0) stx(ws + O_HNEW0 + (size_t)b * 384 + h, hn);
    else { stx(ws + O_HNEW1 + (size_t)b * 384 + h, hn); ws[O_OUTHS + tb * 768 + h] = hn; }
  }
}

__device__ void per_b_predict(int tau, int b, const ScanArgs& A, float* sm) {
  float* ws = A.ws;
  const int tid = threadIdx.x;
  const size_t tb = (size_t)tau * 32 + b;
  float* pmem = ws + O_PMEM + (size_t)b * 15 * 384;
  float* keyl = sm; float* logit = sm + 384; float* att = sm + 400;
  for (int h = tid; h < 384; h += 256)
    keyl[h] = ldx(ws + O_PKEYH + (size_t)b * 384 + h)
            + ldx(ws + O_PKEYMH + (size_t)(tau & 1) * 12288 + (size_t)b * 384 + h);
  __syncthreads();
  {
    int s = tid >> 4, l = tid & 15;
    if (s < 15) {
      const float* mh = pmem + ((tau + s) % 15) * 384;
      float p = 0.f;
      for (int k = l; k < 384; k += 16) p += mh[k] * keyl[k];
      p += __shfl_down(p, 8, 64); p += __shfl_down(p, 4, 64);
      p += __shfl_down(p, 2, 64); p += __shfl_down(p, 1, 64);
      if (l == 0) logit[s] = p * INV_SQRT_H;
    }
  }
  __syncthreads();
  if (tid == 0) {
    const float* mgp = ws + O_MGN + tb * 15;
    float m = logit[0];
    for (int i = 1; i < 15; ++i) m = fmaxf(m, logit[i]);
    float sum = 0.f;
    for (int i = 0; i < 15; ++i) { float e = expf(logit[i] - m) * mgp[i]; att[i] = e; sum += e; }
    float inv = 1.f / (sum + 1e-8f);
    for (int i = 0; i < 15; ++i) att[i] *= inv;
  }
  __syncthreads();
  float av[15]; int pidx[15];
#pragma unroll
  for (int i = 0; i < 15; ++i) { av[i] = att[i]; pidx[i] = (tau + i) % 15; }
  for (int h = tid; h < 384; h += 256) {
    float acc = 0.f;
#pragma unroll
    for (int i = 0; i < 15; ++i) acc += av[i] * pmem[pidx[i] * 384 + h];
    ws[O_OUTHS + tb * 768 + 384 + h] = acc;
  }
  __syncthreads();  // all pmem reads done before append overwrites oldest slot
  for (int h = tid; h < 384; h += 256)
    pmem[(tau % 15) * 384 + h] = ldx(ws + O_HNEW1 + (size_t)b * 384 + h);
}

__global__ __launch_bounds__(256) void k_scan(ScanArgs A) {
  __shared__ float sm[7424];
  float* ws = A.ws;
  unsigned* bar = (unsigned*)(ws + O_BAR);
  const int wg = blockIdx.x;
  unsigned bk = 0;
  for (int t = 0; t <= TT; ++t) {
    // ---- Phase 1: per-b layer0 | GEMVs from h_new1(t-1) ----
    if (wg < 32) {
      if (t < TT) per_b_layer(0, t, wg, A, sm);
    } else {
      GJob J[4] = {
        { A.r_whh + 589824, 384, 0, nullptr, ws + O_P1 + (size_t)((t + 14) % 15) * 1536, 23040, 1536 },
        { A.r_proj_w + 294912, 768, 384, nullptr, ws + O_KEY1MH, 384, 384 },
        { A.p_proj_w, 768, 0, A.p_proj_b, ws + O_PKEYH, 384, 384 },
        { A.p_proj_w, 768, 384, nullptr, ws + O_PKEYMH + (size_t)(t & 1) * 12288, 384, 384 },
      };
      gemm_phase(ws + O_HNEW1, J, 2688, wg - 32, sm);
    }
    grid_barrier(bar, wg, bk); ++bk;
    // ---- Phase 2: per-b predict-att(t-1) | GEMVs from h_new0(t) ----
    if (wg < 32) {
      if (t >= 1) per_b_predict(t - 1, wg, A, sm);
    } else if (t < TT) {
      GJob J[4] = {
        { A.r_wih + 589824, 384, 0, A.r_bih + 1536, ws + O_IH1RAW, 1536, 1536 },
        { A.r_proj_w + 294912, 768, 0, A.r_proj_b + 384, ws + O_KEY1H, 384, 384 },
        { nullptr, 0, 0, nullptr, nullptr, 0, 0 },
        { nullptr, 0, 0, nullptr, nullptr, 0, 0 },
      };
      gemm_phase(ws + O_HNEW0, J, 1920, wg - 32, sm);
    }
    if (t == TT) break;
    grid_barrier(bar, wg, bk); ++bk;
    // ---- Phase 3: per-b layer1 | GEMVs from h_new0(t) for next step ----
    if (wg < 32) {
      per_b_layer(1, t, wg, A, sm);
    } else {
      GJob J[4] = {
        { A.r_whh, 384, 0, nullptr, ws + O_P0 + (size_t)(t % 15) * 1536, 23040, 1536 },
        { A.r_proj_w, 768, 384, nullptr, ws + O_KEY0MH, 384, 384 },
        { nullptr, 0, 0, nullptr, nullptr, 0, 0 },
        { nullptr, 0, 0, nullptr, nullptr, 0, 0 },
      };
      gemm_phase(ws + O_HNEW0, J, 1920, wg - 32, sm);
    }
    grid_barrier(bar, wg, bk); ++bk;
  }
}

// ---------------------------------------------------------------- launch
extern "C" void kernel_launch(void* const* d_in, const int* in_sizes, int n_in,
                              void* d_out, int out_size, void* d_ws, size_t ws_size,
                              hipStream_t stream) {
  const int* ids = (const int*)d_in[0];
  const float* emb_w = (const float*)d_in[1];
  const float* pconv1_w = (const float*)d_in[2];
  const float* pconv1_b = (const float*)d_in[3];
  const float* pbn_g = (const float*)d_in[4];
  const float* pbn_b = (const float*)d_in[5];
  const float* pconv2_w = (const float*)d_in[6];
  const float* pconv2_b = (const float*)d_in[7];
  const float* r_wih = (const float*)d_in[8];
  const float* r_bih = (const float*)d_in[9];
  const float* r_whh = (const float*)d_in[10];
  const float* r_bhh = (const float*)d_in[11];
  const float* r_lnih_g = (const float*)d_in[12];
  const float* r_lnih_b = (const float*)d_in[13];
  const float* r_lnhh_g = (const float*)d_in[14];
  const float* r_lnhh_b = (const float*)d_in[15];
  const float* r_lnc_g = (const float*)d_in[16];
  const float* r_lnc_b = (const float*)d_in[17];
  const float* r_proj_w = (const float*)d_in[18];
  const float* r_proj_b = (const float*)d_in[19];
  const float* p_proj_w = (const float*)d_in[20];
  const float* p_proj_b = (const float*)d_in[21];
  const float* p_ffd_w = (const float*)d_in[22];
  const float* p_ffd_b = (const float*)d_in[23];
  const float* p_bn_g = (const float*)d_in[24];
  const float* p_bn_b = (const float*)d_in[25];
  float* ws = (float*)d_ws;
  float* out = (float*)d_out;

  k_zero<<<1024, 256, 0, stream>>>(ws + O_MEMH0, (int)(O_WSEND - O_MEMH0));
  k_emb<<<4096, 256, 0, stream>>>(ids, emb_w, ws + O_EMB, out);
  k_conv<<<dim3(6, 96), 256, 0, stream>>>(ws + O_EMB, pconv1_w, pconv1_b, pbn_g, pbn_b, ws + O_H1);
  k_gate<<<6144, 256, 0, stream>>>(ws + O_H1, pconv2_w, pconv2_b, ws + O_GATEA, ws + O_GATEB);
  k_mg<<<24, 256, 0, stream>>>(ws + O_GATEA, ws + O_GATEB, ws + O_MG, ws + O_MGN);
  // precompute LN(e@Wih0+b) and key0_e = e@proj0_h + b for all t
  k_gemm<<<dim3(24, 96), 256, 0, stream>>>(ws + O_EMB, 384, r_wih, 384, r_bih,
                                           ws + O_IH0LN, 1536, 384, 0, nullptr, nullptr, nullptr);
  k_gemm<<<dim3(6, 96), 256, 0, stream>>>(ws + O_EMB, 384, r_proj_w, 768, r_proj_b,
                                          ws + O_KEY0E, 384, 384, 0, nullptr, nullptr, nullptr);
  k_ln_rows<<<6144, 256, 0, stream>>>(ws + O_IH0LN, r_lnih_g, r_lnih_b);
  ScanArgs SA{ws, r_whh, r_bhh, r_lnhh_g, r_lnhh_b, r_lnih_g, r_lnih_b,
              r_lnc_g, r_lnc_b, r_wih, r_bih, r_proj_w, r_proj_b, p_proj_w, p_proj_b};
  k_scan<<<128, 256, 0, stream>>>(SA);
  // head: y = tanh(BN(flat @ p_ffd^T + b)) -> out
  k_gemm<<<dim3(6, 96), 256, 0, stream>>>(ws + O_OUTHS, 768, p_ffd_w, 768, p_ffd_b,
                                          nullptr, 384, 768, 1, p_bn_g, p_bn_b, out);
}

// Round 5
// 14267.001 us; speedup vs baseline: 2.3692x; 1.0618x over previous
//
#include <hip/hip_runtime.h>

// PRPN eval forward for MI355X. All float inputs are FP32, ids int32.
// Output = [y (T*B*D) | mask (T*B)] fp32.
//
// R5 vs R4:
//  - GEMV x-vector is staged into LDS via coalesced LLC loads (was: per-lane
//    transposed gather = 64 lines/instruction = ~6 TB/s of LLC line refetch).
//  - red[] reduction buffer padded to stride 33 (R4's coalesced-store reorder
//    created ~28-way LDS bank conflicts: 1.98e8 SQ_LDS_BANK_CONFLICT).
//  - grid 128 -> 256 wgs (32 per-b + 224 GEMV, ragged col split); barrier is
//    16 groups x 16 wgs, monotone relaxed counters on padded lines.

#define TT 192
#define TB 6144

constexpr size_t O_EMB    = 0;          // T*B*384 fp32
constexpr size_t O_IH0LN  = 2359296;    // T*B*1536 (raw then LN'd in place)
constexpr size_t O_KEY0E  = 11796480;   // T*B*384
constexpr size_t O_MG     = 14155776;   // T*B*15
constexpr size_t O_MGN    = 14247936;   // T*B*15
constexpr size_t O_H1     = 14340096;   // B*T x 384 (conv activations, b-major rows)
constexpr size_t O_GATEA  = 16699392;   // B*T
constexpr size_t O_GATEB  = 16705536;   // B*T
constexpr size_t O_OUTHS  = 16711680;   // T*B x 768 (h | sel)
constexpr size_t O_MEMH0  = 21430272;   // state (zeroed): B x 15 x 384 each
constexpr size_t O_MEMC0  = 21614592;
constexpr size_t O_MEMH1  = 21798912;
constexpr size_t O_MEMC1  = 21983232;
constexpr size_t O_PMEM   = 22167552;
constexpr size_t O_P0     = 22351872;   // B x 15 x 1536
constexpr size_t O_P1     = 23089152;
constexpr size_t O_HNEW0  = 23826432;   // B x 384
constexpr size_t O_HNEW1  = 23838720;
constexpr size_t O_IH1RAW = 23851008;   // B x 1536
constexpr size_t O_KEY1H  = 23900160;
constexpr size_t O_KEY0MH = 23912448;
constexpr size_t O_KEY1MH = 23924736;
constexpr size_t O_PKEYH  = 23937024;
constexpr size_t O_PKEYMH = 23949312;   // 2 x B x 384 (ping-pong)
constexpr size_t O_BAR    = 23973888;   // barrier counters (544 u32, padded)
constexpr size_t O_WSEND  = 23974432;

__device__ __forceinline__ float sigmoidf(float x) { return 1.f / (1.f + expf(-x)); }

// LLC-coherent (bypass per-XCD L2) relaxed accessors for cross-wg exchange.
__device__ __forceinline__ float ldx(const float* p) {
  return __hip_atomic_load(p, __ATOMIC_RELAXED, __HIP_MEMORY_SCOPE_AGENT);
}
__device__ __forceinline__ void stx(float* p, float v) {
  __hip_atomic_store(p, v, __ATOMIC_RELAXED, __HIP_MEMORY_SCOPE_AGENT);
}
__device__ __forceinline__ unsigned ldu(const unsigned* p) {
  return __hip_atomic_load(p, __ATOMIC_RELAXED, __HIP_MEMORY_SCOPE_AGENT);
}

constexpr float BN_SC = 0.9999950000374997f;       // 1/sqrt(1+1e-5)
constexpr float INV_SQRT_H = 0.05103103630798288f; // 1/sqrt(384)

__device__ __forceinline__ float blockSum(float v, float* red) {
#pragma unroll
  for (int off = 32; off > 0; off >>= 1) v += __shfl_down(v, off, 64);
  __syncthreads();
  if ((threadIdx.x & 63) == 0) red[threadIdx.x >> 6] = v;
  __syncthreads();
  return red[0] + red[1] + red[2] + red[3];
}

// ---------------------------------------------------------------- k_zero
__global__ __launch_bounds__(256) void k_zero(float* p, int n) {
  int i = blockIdx.x * 256 + threadIdx.x;
  int stride = gridDim.x * 256;
  for (; i < n; i += stride) p[i] = 0.f;
}

// ---------------------------------------------------------------- k_emb (+mask)
__global__ __launch_bounds__(256) void k_emb(const int* ids, const float* emb_w,
                                             float* emb, float* out) {
  size_t idx = (size_t)blockIdx.x * 256 + threadIdx.x;
  size_t stride = (size_t)gridDim.x * 256;
  for (size_t i = idx; i < (size_t)TB * 384; i += stride) {
    size_t tb = i / 384, d = i - tb * 384;
    int id = ids[tb];
    emb[i] = emb_w[(size_t)id * 384 + d];
    if (i < TB) out[(size_t)TB * 384 + i] = (ids[i] != 0) ? 1.f : 0.f;
  }
}

// ---------------------------------------------------------------- k_conv (im2col GEMM)
__global__ __launch_bounds__(256) void k_conv(const float* emb, const float* W1, const float* cbias,
                                              const float* bng, const float* bnb, float* h1) {
  __shared__ float As[32][68];
  __shared__ float Bs[32][68];
  int n0 = blockIdx.x * 64, m0 = blockIdx.y * 64;
  int tid = threadIdx.x;
  float acc[4][4] = {};
  int mi = tid >> 3, kq = tid & 7;
  int ni = tid >> 2, kb = tid & 3;
  for (int kk = 0; kk < 2304; kk += 32) {
    int kc = kk / 384, dbase = kk - kc * 384;
    __syncthreads();
#pragma unroll
    for (int p = 0; p < 2; ++p) {
      int m = m0 + mi + 32 * p;
      int b = m / 192, t = m - b * 192;
      int tt = t + kc - 5;
      float4 v = {0.f, 0.f, 0.f, 0.f};
      if (tt >= 0) v = *(const float4*)(emb + ((size_t)tt * 32 + b) * 384 + dbase + kq * 4);
      As[kq * 4 + 0][mi + 32 * p] = v.x; As[kq * 4 + 1][mi + 32 * p] = v.y;
      As[kq * 4 + 2][mi + 32 * p] = v.z; As[kq * 4 + 3][mi + 32 * p] = v.w;
    }
#pragma unroll
    for (int i = 0; i < 8; ++i) {
      int d = dbase + kb * 8 + i;
      Bs[kb * 8 + i][ni] = W1[(size_t)(n0 + ni) * 2304 + d * 6 + kc];
    }
    __syncthreads();
    int ty = tid >> 4, tx = tid & 15;
#pragma unroll
    for (int k = 0; k < 32; ++k) {
      float4 a = *(const float4*)(&As[k][ty * 4]);
      float4 bv = *(const float4*)(&Bs[k][tx * 4]);
      acc[0][0] += a.x * bv.x; acc[0][1] += a.x * bv.y; acc[0][2] += a.x * bv.z; acc[0][3] += a.x * bv.w;
      acc[1][0] += a.y * bv.x; acc[1][1] += a.y * bv.y; acc[1][2] += a.y * bv.z; acc[1][3] += a.y * bv.w;
      acc[2][0] += a.z * bv.x; acc[2][1] += a.z * bv.y; acc[2][2] += a.z * bv.z; acc[2][3] += a.z * bv.w;
      acc[3][0] += a.w * bv.x; acc[3][1] += a.w * bv.y; acc[3][2] += a.w * bv.z; acc[3][3] += a.w * bv.w;
    }
  }
  int ty = tid >> 4, tx = tid & 15;
#pragma unroll
  for (int i = 0; i < 4; ++i) {
    int m = m0 + ty * 4 + i;
#pragma unroll
    for (int j = 0; j < 4; ++j) {
      int n = n0 + tx * 4 + j;
      float v = acc[i][j] + cbias[n];
      v = bng[n] * v * BN_SC + bnb[n];
      h1[(size_t)m * 384 + n] = fmaxf(v, 0.f);
    }
  }
}

// ---------------------------------------------------------------- k_gate
__global__ __launch_bounds__(256) void k_gate(const float* h1, const float* w2, const float* b2,
                                              float* gA, float* gB) {
  __shared__ float red[8];
  int bt = blockIdx.x, tid = threadIdx.x;
  float v0 = 0.f, v1 = 0.f;
  if (tid < 192) {
    v0 = h1[(size_t)bt * 384 + tid] * w2[tid];
    v1 = h1[(size_t)bt * 384 + 192 + tid] * w2[192 + tid];
  }
  float s0 = blockSum(v0, red);
  float s1 = blockSum(v1, red);
  if (tid == 0) {
    gA[bt] = 1.f / (1.f + expf(-(s0 + b2[0])));
    gB[bt] = 1.f / (1.f + expf(-(s1 + b2[1])));
  }
}

// ---------------------------------------------------------------- k_mg (hard gates + cumprod)
__global__ __launch_bounds__(256) void k_mg(const float* gA, const float* gB, float* mg, float* mgn) {
  int idx = blockIdx.x * 256 + threadIdx.x;
  if (idx >= TB) return;
  int t = idx >> 5, b = idx & 31;
  float g = gA[b * 192 + t], gn = gB[b * 192 + t];
  float p = 1.f, pn = 1.f;
  for (int k = 0; k < 15; ++k) {
    float ghat = (k <= t) ? gA[b * 192 + t - k] : 1e9f;
    float u = fminf(fmaxf((g - ghat) / 0.1f * 2.f + 1.f, -1.f), 1.f);
    float un = fminf(fmaxf((gn - ghat) / 0.1f * 2.f + 1.f, -1.f), 1.f);
    p *= (u + 1.f) * 0.5f;
    pn *= (un + 1.f) * 0.5f;
    mg[(size_t)idx * 15 + k] = p;
    mgn[(size_t)idx * 15 + k] = pn;
  }
}

// ---------------------------------------------------------------- k_gemm (generic)
__global__ __launch_bounds__(256) void k_gemm(const float* A, int lda, const float* W, int ldw,
                                              const float* bias, float* Cf, int ldc, int K, int mode,
                                              const float* bng, const float* bnb, float* Cb) {
  __shared__ float As[32][68];
  __shared__ float Bs[32][68];
  int n0 = blockIdx.x * 64, m0 = blockIdx.y * 64;
  int tid = threadIdx.x;
  float acc[4][4] = {};
  int mi = tid >> 3, kq = tid & 7;
  int ni = tid >> 2, kb = tid & 3;
  for (int kk = 0; kk < K; kk += 32) {
    __syncthreads();
#pragma unroll
    for (int p = 0; p < 2; ++p) {
      int m = m0 + mi + 32 * p;
      float4 v = *(const float4*)(A + (size_t)m * lda + kk + kq * 4);
      As[kq * 4 + 0][mi + 32 * p] = v.x; As[kq * 4 + 1][mi + 32 * p] = v.y;
      As[kq * 4 + 2][mi + 32 * p] = v.z; As[kq * 4 + 3][mi + 32 * p] = v.w;
    }
    {
      const float* wp = W + (size_t)(n0 + ni) * ldw + kk + kb * 8;
      float4 q0 = *(const float4*)(wp);
      float4 q1 = *(const float4*)(wp + 4);
      Bs[kb * 8 + 0][ni] = q0.x; Bs[kb * 8 + 1][ni] = q0.y;
      Bs[kb * 8 + 2][ni] = q0.z; Bs[kb * 8 + 3][ni] = q0.w;
      Bs[kb * 8 + 4][ni] = q1.x; Bs[kb * 8 + 5][ni] = q1.y;
      Bs[kb * 8 + 6][ni] = q1.z; Bs[kb * 8 + 7][ni] = q1.w;
    }
    __syncthreads();
    int ty = tid >> 4, tx = tid & 15;
#pragma unroll
    for (int k = 0; k < 32; ++k) {
      float4 a = *(const float4*)(&As[k][ty * 4]);
      float4 bv = *(const float4*)(&Bs[k][tx * 4]);
      acc[0][0] += a.x * bv.x; acc[0][1] += a.x * bv.y; acc[0][2] += a.x * bv.z; acc[0][3] += a.x * bv.w;
      acc[1][0] += a.y * bv.x; acc[1][1] += a.y * bv.y; acc[1][2] += a.y * bv.z; acc[1][3] += a.y * bv.w;
      acc[2][0] += a.z * bv.x; acc[2][1] += a.z * bv.y; acc[2][2] += a.z * bv.z; acc[2][3] += a.z * bv.w;
      acc[3][0] += a.w * bv.x; acc[3][1] += a.w * bv.y; acc[3][2] += a.w * bv.z; acc[3][3] += a.w * bv.w;
    }
  }
  int ty = tid >> 4, tx = tid & 15;
#pragma unroll
  for (int i = 0; i < 4; ++i) {
    int m = m0 + ty * 4 + i;
#pragma unroll
    for (int j = 0; j < 4; ++j) {
      int n = n0 + tx * 4 + j;
      float v = acc[i][j];
      if (bias) v += bias[n];
      if (mode == 0) Cf[(size_t)m * ldc + n] = v;
      else Cb[(size_t)m * ldc + n] = tanhf(bng[n] * v * BN_SC + bnb[n]);
    }
  }
}

// ---------------------------------------------------------------- k_ln_rows
__global__ __launch_bounds__(256) void k_ln_rows(float* X, const float* g, const float* bt) {
  __shared__ float red[8];
  float* x = X + (size_t)blockIdx.x * 1536;
  int tid = threadIdx.x;
  float ps = 0.f;
  for (int i = tid; i < 1536; i += 256) ps += x[i];
  float mu = blockSum(ps, red) * (1.f / 1536.f);
  ps = 0.f;
  for (int i = tid; i < 1536; i += 256) { float d = x[i] - mu; ps += d * d; }
  float inv = 1.f / (sqrtf(blockSum(ps, red) * (1.f / 1535.f)) + 1e-6f);
  for (int i = tid; i < 1536; i += 256) x[i] = g[i] * (x[i] - mu) * inv + bt[i];
}

// ---------------------------------------------------------------- scan kernel
struct ScanArgs {
  float* ws;
  const float *r_whh, *r_bhh, *r_lnhh_g, *r_lnhh_b, *r_lnih_g, *r_lnih_b;
  const float *r_lnc_g, *r_lnc_b, *r_wih, *r_bih, *r_proj_w, *r_proj_b;
  const float *p_proj_w, *p_proj_b;
};

struct GJob { const float* W; int ldw; int koff; const float* bias; float* dst; int rstride; int ncols; };

__device__ __forceinline__ void resolveJob(const GJob* J, int col, const float*& W, int& ldw, int& koff,
                                           const float*& bias, float*& dst, int& rstride, int& cc) {
  int c = col;
#pragma unroll
  for (int j = 0; j < 4; ++j) {
    if (c < J[j].ncols) {
      W = J[j].W; ldw = J[j].ldw; koff = J[j].koff; bias = J[j].bias;
      dst = J[j].dst; rstride = J[j].rstride; cc = c; return;
    }
    c -= J[j].ncols;
  }
  W = J[0].W; ldw = J[0].ldw; koff = J[0].koff; bias = J[0].bias;
  dst = J[0].dst; rstride = J[0].rstride; cc = 0;
}

// Hierarchical monotone-counter barrier: 16 groups x 16 wgs, counters on
// separate 64B lines, all relaxed (monotone -> no reset race).
// Layout (u32): grp_cnt[g]=g*16 (g<16), root_cnt=256, root_gen=272, grp_gen[g]=288+g*16.
__device__ void grid_barrier(unsigned* bar, int wg, unsigned k) {
  __syncthreads();
  if (threadIdx.x == 0) {
    const int g = wg >> 4;
    unsigned arr = __hip_atomic_fetch_add(bar + g * 16, 1u, __ATOMIC_RELAXED, __HIP_MEMORY_SCOPE_AGENT);
    if (arr == k * 16u + 15u) {                       // group leader
      unsigned ra = __hip_atomic_fetch_add(bar + 256, 1u, __ATOMIC_RELAXED, __HIP_MEMORY_SCOPE_AGENT);
      if (ra == k * 16u + 15u) {
        __hip_atomic_store(bar + 272, k + 1u, __ATOMIC_RELAXED, __HIP_MEMORY_SCOPE_AGENT);
      } else {
        while (ldu(bar + 272) < k + 1u) __builtin_amdgcn_s_sleep(2);
      }
      __hip_atomic_store(bar + 288 + g * 16, k + 1u, __ATOMIC_RELAXED, __HIP_MEMORY_SCOPE_AGENT);
    } else {
      while (ldu(bar + 288 + g * 16) < k + 1u) __builtin_amdgcn_s_sleep(8);
    }
  }
  __syncthreads();
}

// weight-shared GEMV phase: cols ragged-split over NG wgs, K=384 split over 8
// thread-groups, partials in LDS (stride-33 pad). x staged to LDS via
// coalesced LLC loads (stride-385 pad). Weights: plain loads (L2-resident).
#define NG_GEMV 224
__device__ void gemm_phase(const float* src, const GJob* J, int NC, int gwg,
                           float* xs /*32*385*/, float* red /*8*14*33*/) {
  const int tid = threadIdx.x;
  // stage x: 32x384, lane-consecutive addresses -> few LLC lines per inst
  for (int j = tid; j < 12288; j += 256) {
    int bb = j >> 8;                 // j / 384 avoided: do exact div
    bb = j / 384;
    int kk = j - bb * 384;
    xs[bb * 385 + kk] = ldx(src + j);
  }
  __syncthreads();
  const int b = tid & 31, cg = tid >> 5;
  const int c0 = (gwg * NC) / NG_GEMV, c1 = ((gwg + 1) * NC) / NG_GEMV;
  const int colsPer = c1 - c0;
  const int k0 = cg * 48;
  float xr[48];
  const float* xp = xs + b * 385 + k0;   // bank = (b + k) % 32: conflict-free
#pragma unroll
  for (int q = 0; q < 48; ++q) xr[q] = xp[q];
  for (int ci = 0; ci < colsPer; ++ci) {
    const float* W; int ldw, koff; const float* bias; float* dst; int rstride; int cc;
    resolveJob(J, c0 + ci, W, ldw, koff, bias, dst, rstride, cc);
    const float* wr = W + (size_t)cc * ldw + koff + k0;
    float a = 0.f;
#pragma unroll
    for (int q = 0; q < 12; ++q) {
      float4 w = *(const float4*)(wr + q * 4);
      a += w.x * xr[q * 4 + 0] + w.y * xr[q * 4 + 1]
         + w.z * xr[q * 4 + 2] + w.w * xr[q * 4 + 3];
    }
    red[(cg * colsPer + ci) * 33 + b] = a;
  }
  __syncthreads();
  const int pairs = colsPer * 32;
  // coalesced: consecutive lanes -> consecutive cc of the same output row;
  // LDS read bank = (g*colsPer+ci + bb) % 32 -> conflict-free (pad 33)
  for (int pi = tid; pi < pairs; pi += 256) {
    int bb = pi / colsPer, ci = pi - bb * colsPer;
    float s = 0.f;
#pragma unroll
    for (int g = 0; g < 8; ++g) s += red[(g * colsPer + ci) * 33 + bb];
    const float* W; int ldw, koff; const float* bias; float* dst; int rstride; int cc;
    resolveJob(J, c0 + ci, W, ldw, koff, bias, dst, rstride, cc);
    if (bias) s += bias[cc];
    stx(dst + (size_t)bb * rstride + cc, s);
  }
  __syncthreads();
}

// per-batch phase: attention (msoftmax with hard gate), P-cache combine,
// LayerNorms, LSTM cell, LN(c), memory append.
__device__ void per_b_layer(int layer, int t, int b, const ScanArgs& A, float* sm) {
  float* ws = A.ws;
  const int tid = threadIdx.x;
  const size_t tb = (size_t)t * 32 + b;
  float* memh = ws + (layer ? O_MEMH1 : O_MEMH0) + (size_t)b * 15 * 384;
  float* memc = ws + (layer ? O_MEMC1 : O_MEMC0) + (size_t)b * 15 * 384;
  float* P = ws + (layer ? O_P1 : O_P0) + (size_t)b * 15 * 1536;
  float* keyl = sm; float* logit = sm + 384; float* att = sm + 400; float* red = sm + 416;
  float* ghh = sm + 448; float* gih = sm + 1984; float* selc = sm + 3520;
  float* cnew = sm + 3904; float* ogat = sm + 4288;

  for (int h = tid; h < 384; h += 256) {
    float k1, k2;
    if (layer == 0) { k1 = ws[O_KEY0E + tb * 384 + h]; k2 = ldx(ws + O_KEY0MH + (size_t)b * 384 + h); }
    else { k1 = ldx(ws + O_KEY1H + (size_t)b * 384 + h); k2 = ldx(ws + O_KEY1MH + (size_t)b * 384 + h); }
    keyl[h] = k1 + k2;
  }
  __syncthreads();
  {
    int s = tid >> 4, l = tid & 15;
    if (s < 15) {
      const float* mh = memh + ((t + s) % 15) * 384;
      float p = 0.f;
      for (int k = l; k < 384; k += 16) p += mh[k] * keyl[k];
      p += __shfl_down(p, 8, 64); p += __shfl_down(p, 4, 64);
      p += __shfl_down(p, 2, 64); p += __shfl_down(p, 1, 64);
      if (l == 0) logit[s] = p * INV_SQRT_H;
    }
  }
  __syncthreads();
  if (tid == 0) {
    const float* mgp = ws + O_MG + tb * 15;
    float m = logit[0];
    for (int i = 1; i < 15; ++i) m = fmaxf(m, logit[i]);
    float sum = 0.f;
    for (int i = 0; i < 15; ++i) { float e = expf(logit[i] - m) * mgp[i]; att[i] = e; sum += e; }
    float inv = 1.f / (sum + 1e-8f);
    for (int i = 0; i < 15; ++i) att[i] *= inv;
  }
  __syncthreads();
  float av[15]; int pidx[15];
#pragma unroll
  for (int i = 0; i < 15; ++i) { av[i] = att[i]; pidx[i] = (t + i) % 15; }
  const float* bhh = A.r_bhh + layer * 1536;
  for (int n = tid; n < 1536; n += 256) {
    float acc = bhh[n];
#pragma unroll
    for (int i = 0; i < 15; ++i) acc += av[i] * ldx(P + (size_t)pidx[i] * 1536 + n);
    ghh[n] = acc;
  }
  for (int h = tid; h < 384; h += 256) {
    float acc = 0.f;
#pragma unroll
    for (int i = 0; i < 15; ++i) acc += av[i] * memc[pidx[i] * 384 + h];
    selc[h] = acc;
  }
  if (layer) {
    for (int n = tid; n < 1536; n += 256) gih[n] = ldx(ws + O_IH1RAW + (size_t)b * 1536 + n);
  }
  __syncthreads();
  float ps = 0.f;
  for (int n = tid; n < 1536; n += 256) ps += ghh[n];
  float mu_hh = blockSum(ps, red) * (1.f / 1536.f);
  ps = 0.f;
  for (int n = tid; n < 1536; n += 256) { float d = ghh[n] - mu_hh; ps += d * d; }
  float inv_hh = 1.f / (sqrtf(blockSum(ps, red) * (1.f / 1535.f)) + 1e-6f);
  float mu_ih = 0.f, inv_ih = 0.f;
  if (layer) {
    ps = 0.f;
    for (int n = tid; n < 1536; n += 256) ps += gih[n];
    mu_ih = blockSum(ps, red) * (1.f / 1536.f);
    ps = 0.f;
    for (int n = tid; n < 1536; n += 256) { float d = gih[n] - mu_ih; ps += d * d; }
    inv_ih = 1.f / (sqrtf(blockSum(ps, red) * (1.f / 1535.f)) + 1e-6f);
  }
  const float *hg = A.r_lnhh_g + layer * 1536, *hb = A.r_lnhh_b + layer * 1536;
  const float *ig = A.r_lnih_g + 1536, *ib = A.r_lnih_b + 1536;
  for (int h = tid; h < 384; h += 256) {
    float gi, gf, gc, go;
    if (layer == 0) {
      const float* ihr = ws + O_IH0LN + tb * 1536;
      gi = ihr[h]; gf = ihr[384 + h]; gc = ihr[768 + h]; go = ihr[1152 + h];
    } else {
      gi = ig[h] * (gih[h] - mu_ih) * inv_ih + ib[h];
      gf = ig[384 + h] * (gih[384 + h] - mu_ih) * inv_ih + ib[384 + h];
      gc = ig[768 + h] * (gih[768 + h] - mu_ih) * inv_ih + ib[768 + h];
      go = ig[1152 + h] * (gih[1152 + h] - mu_ih) * inv_ih + ib[1152 + h];
    }
    gi += hg[h] * (ghh[h] - mu_hh) * inv_hh + hb[h];
    gf += hg[384 + h] * (ghh[384 + h] - mu_hh) * inv_hh + hb[384 + h];
    gc += hg[768 + h] * (ghh[768 + h] - mu_hh) * inv_hh + hb[768 + h];
    go += hg[1152 + h] * (ghh[1152 + h] - mu_hh) * inv_hh + hb[1152 + h];
    float c = sigmoidf(gf) * selc[h] + sigmoidf(gi) * tanhf(gc);
    cnew[h] = c; ogat[h] = go;
  }
  __syncthreads();
  ps = 0.f;
  for (int h = tid; h < 384; h += 256) ps += cnew[h];
  float mu_c = blockSum(ps, red) * (1.f / 384.f);
  ps = 0.f;
  for (int h = tid; h < 384; h += 256) { float d = cnew[h] - mu_c; ps += d * d; }
  float inv_c = 1.f / (sqrtf(blockSum(ps, red) * (1.f / 383.f)) + 1e-6f);
  const float *lcg = A.r_lnc_g + layer * 384, *lcb = A.r_lnc_b + layer * 384;
  const int slot = t % 15;
  for (int h = tid; h < 384; h += 256) {
    float hn = sigmoidf(ogat[h]) * tanhf(lcg[h] * (cnew[h] - mu_c) * inv_c + lcb[h]);
    memh[slot * 384 + h] = hn;
    memc[slot * 384 + h] = cnew[h];
    if (layer == 0) stx(ws + O_HNEW0 + (size_t)b * 384 + h, hn);
    else { stx(ws + O_HNEW1 + (size_t)b * 384 + h, hn); ws[O_OUTHS + tb * 768 + h] = hn; }
  }
}

__device__ void per_b_predict(int tau, int b, const ScanArgs& A, float* sm) {
  float* ws = A.ws;
  const int tid = threadIdx.x;
  const size_t tb = (size_t)tau * 32 + b;
  float* pmem = ws + O_PMEM + (size_t)b * 15 * 384;
  float* keyl = sm; float* logit = sm + 384; float* att = sm + 400;
  for (int h = tid; h < 384; h += 256)
    keyl[h] = ldx(ws + O_PKEYH + (size_t)b * 384 + h)
            + ldx(ws + O_PKEYMH + (size_t)(tau & 1) * 12288 + (size_t)b * 384 + h);
  __syncthreads();
  {
    int s = tid >> 4, l = tid & 15;
    if (s < 15) {
      const float* mh = pmem + ((tau + s) % 15) * 384;
      float p = 0.f;
      for (int k = l; k < 384; k += 16) p += mh[k] * keyl[k];
      p += __shfl_down(p, 8, 64); p += __shfl_down(p, 4, 64);
      p += __shfl_down(p, 2, 64); p += __shfl_down(p, 1, 64);
      if (l == 0) logit[s] = p * INV_SQRT_H;
    }
  }
  __syncthreads();
  if (tid == 0) {
    const float* mgp = ws + O_MGN + tb * 15;
    float m = logit[0];
    for (int i = 1; i < 15; ++i) m = fmaxf(m, logit[i]);
    float sum = 0.f;
    for (int i = 0; i < 15; ++i) { float e = expf(logit[i] - m) * mgp[i]; att[i] = e; sum += e; }
    float inv = 1.f / (sum + 1e-8f);
    for (int i = 0; i < 15; ++i) att[i] *= inv;
  }
  __syncthreads();
  float av[15]; int pidx[15];
#pragma unroll
  for (int i = 0; i < 15; ++i) { av[i] = att[i]; pidx[i] = (tau + i) % 15; }
  for (int h = tid; h < 384; h += 256) {
    float acc = 0.f;
#pragma unroll
    for (int i = 0; i < 15; ++i) acc += av[i] * pmem[pidx[i] * 384 + h];
    ws[O_OUTHS + tb * 768 + 384 + h] = acc;
  }
  __syncthreads();  // all pmem reads done before append overwrites oldest slot
  for (int h = tid; h < 384; h += 256)
    pmem[(tau % 15) * 384 + h] = ldx(ws + O_HNEW1 + (size_t)b * 384 + h);
}

__global__ __launch_bounds__(256) void k_scan(ScanArgs A) {
  __shared__ float sm[16032];           // per_b: <4672 | gemv: xs 12320 + red 3696
  float* ws = A.ws;
  unsigned* bar = (unsigned*)(ws + O_BAR);
  const int wg = blockIdx.x;
  float* xs = sm;
  float* red = sm + 12320;
  unsigned bk = 0;
  for (int t = 0; t <= TT; ++t) {
    // ---- Phase 1: per-b layer0 | GEMVs from h_new1(t-1) ----
    if (wg < 32) {
      if (t < TT) per_b_layer(0, t, wg, A, sm);
    } else {
      GJob J[4] = {
        { A.r_whh + 589824, 384, 0, nullptr, ws + O_P1 + (size_t)((t + 14) % 15) * 1536, 23040, 1536 },
        { A.r_proj_w + 294912, 768, 384, nullptr, ws + O_KEY1MH, 384, 384 },
        { A.p_proj_w, 768, 0, A.p_proj_b, ws + O_PKEYH, 384, 384 },
        { A.p_proj_w, 768, 384, nullptr, ws + O_PKEYMH + (size_t)(t & 1) * 12288, 384, 384 },
      };
      gemm_phase(ws + O_HNEW1, J, 2688, wg - 32, xs, red);
    }
    grid_barrier(bar, wg, bk); ++bk;
    // ---- Phase 2: per-b predict-att(t-1) | GEMVs from h_new0(t) ----
    if (wg < 32) {
      if (t >= 1) per_b_predict(t - 1, wg, A, sm);
    } else if (t < TT) {
      GJob J[4] = {
        { A.r_wih + 589824, 384, 0, A.r_bih + 1536, ws + O_IH1RAW, 1536, 1536 },
        { A.r_proj_w + 294912, 768, 0, A.r_proj_b + 384, ws + O_KEY1H, 384, 384 },
        { nullptr, 0, 0, nullptr, nullptr, 0, 0 },
        { nullptr, 0, 0, nullptr, nullptr, 0, 0 },
      };
      gemm_phase(ws + O_HNEW0, J, 1920, wg - 32, xs, red);
    }
    if (t == TT) break;
    grid_barrier(bar, wg, bk); ++bk;
    // ---- Phase 3: per-b layer1 | GEMVs from h_new0(t) for next step ----
    if (wg < 32) {
      per_b_layer(1, t, wg, A, sm);
    } else {
      GJob J[4] = {
        { A.r_whh, 384, 0, nullptr, ws + O_P0 + (size_t)(t % 15) * 1536, 23040, 1536 },
        { A.r_proj_w, 768, 384, nullptr, ws + O_KEY0MH, 384, 384 },
        { nullptr, 0, 0, nullptr, nullptr, 0, 0 },
        { nullptr, 0, 0, nullptr, nullptr, 0, 0 },
      };
      gemm_phase(ws + O_HNEW0, J, 1920, wg - 32, xs, red);
    }
    grid_barrier(bar, wg, bk); ++bk;
  }
}

// ---------------------------------------------------------------- launch
extern "C" void kernel_launch(void* const* d_in, const int* in_sizes, int n_in,
                              void* d_out, int out_size, void* d_ws, size_t ws_size,
                              hipStream_t stream) {
  const int* ids = (const int*)d_in[0];
  const float* emb_w = (const float*)d_in[1];
  const float* pconv1_w = (const float*)d_in[2];
  const float* pconv1_b = (const float*)d_in[3];
  const float* pbn_g = (const float*)d_in[4];
  const float* pbn_b = (const float*)d_in[5];
  const float* pconv2_w = (const float*)d_in[6];
  const float* pconv2_b = (const float*)d_in[7];
  const float* r_wih = (const float*)d_in[8];
  const float* r_bih = (const float*)d_in[9];
  const float* r_whh = (const float*)d_in[10];
  const float* r_bhh = (const float*)d_in[11];
  const float* r_lnih_g = (const float*)d_in[12];
  const float* r_lnih_b = (const float*)d_in[13];
  const float* r_lnhh_g = (const float*)d_in[14];
  const float* r_lnhh_b = (const float*)d_in[15];
  const float* r_lnc_g = (const float*)d_in[16];
  const float* r_lnc_b = (const float*)d_in[17];
  const float* r_proj_w = (const float*)d_in[18];
  const float* r_proj_b = (const float*)d_in[19];
  const float* p_proj_w = (const float*)d_in[20];
  const float* p_proj_b = (const float*)d_in[21];
  const float* p_ffd_w = (const float*)d_in[22];
  const float* p_ffd_b = (const float*)d_in[23];
  const float* p_bn_g = (const float*)d_in[24];
  const float* p_bn_b = (const float*)d_in[25];
  float* ws = (float*)d_ws;
  float* out = (float*)d_out;

  k_zero<<<1024, 256, 0, stream>>>(ws + O_MEMH0, (int)(O_WSEND - O_MEMH0));
  k_emb<<<4096, 256, 0, stream>>>(ids, emb_w, ws + O_EMB, out);
  k_conv<<<dim3(6, 96), 256, 0, stream>>>(ws + O_EMB, pconv1_w, pconv1_b, pbn_g, pbn_b, ws + O_H1);
  k_gate<<<6144, 256, 0, stream>>>(ws + O_H1, pconv2_w, pconv2_b, ws + O_GATEA, ws + O_GATEB);
  k_mg<<<24, 256, 0, stream>>>(ws + O_GATEA, ws + O_GATEB, ws + O_MG, ws + O_MGN);
  // precompute LN(e@Wih0+b) and key0_e = e@proj0_h + b for all t
  k_gemm<<<dim3(24, 96), 256, 0, stream>>>(ws + O_EMB, 384, r_wih, 384, r_bih,
                                           ws + O_IH0LN, 1536, 384, 0, nullptr, nullptr, nullptr);
  k_gemm<<<dim3(6, 96), 256, 0, stream>>>(ws + O_EMB, 384, r_proj_w, 768, r_proj_b,
                                          ws + O_KEY0E, 384, 384, 0, nullptr, nullptr, nullptr);
  k_ln_rows<<<6144, 256, 0, stream>>>(ws + O_IH0LN, r_lnih_g, r_lnih_b);
  ScanArgs SA{ws, r_whh, r_bhh, r_lnhh_g, r_lnhh_b, r_lnih_g, r_lnih_b,
              r_lnc_g, r_lnc_b, r_wih, r_bih, r_proj_w, r_proj_b, p_proj_w, p_proj_b};
  k_scan<<<256, 256, 0, stream>>>(SA);
  // head: y = tanh(BN(flat @ p_ffd^T + b)) -> out
  k_gemm<<<dim3(6, 96), 256, 0, stream>>>(ws + O_OUTHS, 768, p_ffd_w, 768, p_ffd_b,
                                          nullptr, 384, 768, 1, p_bn_g, p_bn_b, out);
}